// Round 1
// baseline (412.611 us; speedup 1.0000x reference)
//
#include <hip/hip_runtime.h>
#include <cstdint>
#include <cstddef>

typedef unsigned short u16;
typedef __bf16 bf16x8 __attribute__((ext_vector_type(8)));
typedef float f32x4 __attribute__((ext_vector_type(4)));

// ---------- constants ----------
#define BATCH 4
#define SEQ   2048
#define DM    768
#define NH    8
#define DK    96
#define DFF   2048
#define MTOK  8192          // BATCH*SEQ
#define QKVN  2304          // 3*DM
#define LOG2E 1.44269504088896340736f

// ---------- helpers ----------
__device__ __forceinline__ u16 f2bf(float f) {
  union { float f; uint32_t u; } v; v.f = f;
  return (u16)((v.u + 0x7fffu + ((v.u >> 16) & 1u)) >> 16);
}
__device__ __forceinline__ float bf2f(u16 b) {
  union { uint32_t u; float f; } v; v.u = (uint32_t)b << 16;
  return v.f;
}
__device__ __forceinline__ bf16x8 ld8(const u16* p) { return *(const bf16x8*)p; }
__device__ __forceinline__ void async16(const u16* g, u16* l) {
  __builtin_amdgcn_global_load_lds((const __attribute__((address_space(1))) void*)g,
                                   (__attribute__((address_space(3))) void*)l, 16, 0, 0);
}

// ---------- fused prep: cast_bf16 + concat3 + 6 weight transposes ----------
__global__ __launch_bounds__(256)
void prep(const float* __restrict__ x, u16* __restrict__ xb,
          const float* __restrict__ bq, const float* __restrict__ bk,
          const float* __restrict__ bv, float* __restrict__ bqkv,
          const float* __restrict__ Wq, const float* __restrict__ Wk,
          const float* __restrict__ Wv, const float* __restrict__ Wo,
          const float* __restrict__ W1, const float* __restrict__ W2,
          u16* __restrict__ WT, u16* __restrict__ WoT,
          u16* __restrict__ W1T, u16* __restrict__ W2T) {
  __shared__ float t[32][33];
  const int tid = threadIdx.x;
  int bid = blockIdx.x;

  if (bid < 6144) {                       // cast x (8192x768 fp32 -> bf16)
    size_t i = (size_t)bid * 1024 + tid * 4;
    float4 f = *(const float4*)(x + i);
    uint2 o;
    o.x = (unsigned)f2bf(f.x) | ((unsigned)f2bf(f.y) << 16);
    o.y = (unsigned)f2bf(f.z) | ((unsigned)f2bf(f.w) << 16);
    *(uint2*)(xb + i) = o;
    return;
  }
  if (bid < 6153) {                       // concat qkv bias (2304)
    int i = (bid - 6144) * 256 + tid;
    float v = (i < 768) ? bq[i] : (i < 1536) ? bk[i - 768] : bv[i - 1536];
    bqkv[i] = v;
    return;
  }
  bid -= 6153;
  const float* in; u16* out; int C, R, bx, by;
  if (bid < 576)       { in = Wq; out = WT;                 C = 768;  R = 768;  bx = bid % 24;          by = bid / 24; }
  else if (bid < 1152) { in = Wk; out = WT + 768 * 768;     C = 768;  R = 768;  bx = (bid - 576) % 24;  by = (bid - 576) / 24; }
  else if (bid < 1728) { in = Wv; out = WT + 2 * 768 * 768; C = 768;  R = 768;  bx = (bid - 1152) % 24; by = (bid - 1152) / 24; }
  else if (bid < 2304) { in = Wo; out = WoT;                C = 768;  R = 768;  bx = (bid - 1728) % 24; by = (bid - 1728) / 24; }
  else if (bid < 3840) { in = W1; out = W1T;                C = 2048; R = 768;  bx = (bid - 2304) % 64; by = (bid - 2304) / 64; }
  else                 { in = W2; out = W2T;                C = 768;  R = 2048; bx = (bid - 3840) % 24; by = (bid - 3840) / 24; }
  const int r0 = by * 32, c0 = bx * 32;
  const int tx = tid & 31, ty = tid >> 5;
#pragma unroll
  for (int i = 0; i < 4; i++)
    t[ty + i * 8][tx] = in[(size_t)(r0 + ty + i * 8) * C + c0 + tx];
  __syncthreads();
#pragma unroll
  for (int i = 0; i < 4; i++)
    out[(size_t)(c0 + ty + i * 8) * R + r0 + tx] = f2bf(t[tx][ty + i * 8]);
}

// v part of qkv (stride 2304) -> vt [B*H][96][2048] bf16
__global__ void transpose_v(const u16* __restrict__ v, u16* __restrict__ vt) {
  __shared__ u16 t[32][33];
  int bh = blockIdx.z, b = bh >> 3, h = bh & 7;
  int s0 = blockIdx.x * 32, d0 = blockIdx.y * 32;
  int tx = threadIdx.x, ty = threadIdx.y;
#pragma unroll
  for (int i = 0; i < 4; i++)
    t[ty + i * 8][tx] = v[(size_t)(b * SEQ + s0 + ty + i * 8) * QKVN + h * DK + d0 + tx];
  __syncthreads();
#pragma unroll
  for (int i = 0; i < 4; i++)
    vt[(size_t)(bh * DK + d0 + ty + i * 8) * SEQ + s0 + tx] = t[tx][ty + i * 8];
}

// ---------- GEMM: C[M,N] = A[M,K] @ BT[N,K]^T + bias (+resid)(+relu) ----------
template <int RESID, int RELU, int OUTBF>
__global__ __launch_bounds__(256, 4)
void gemm_bt(const u16* __restrict__ A, const u16* __restrict__ BT,
             const float* __restrict__ bias, const float* __restrict__ resid,
             float* __restrict__ Cf, u16* __restrict__ Cb, int N, int K) {
  __shared__ __align__(16) u16 lA[128 * 64];
  __shared__ __align__(16) u16 lB[128 * 64];
  const int tid = threadIdx.x;
  const int wave = tid >> 6, lane = tid & 63;
  const int quad = lane >> 4, l16 = lane & 15;
  const int wm = wave >> 1, wn = wave & 1;
  const int tm = blockIdx.y * 128, tn = blockIdx.x * 128;

  f32x4 acc[4][4] = {};

  for (int k0 = 0; k0 < K; k0 += 64) {
    __syncthreads();
#pragma unroll
    for (int i = 0; i < 4; i++) {
      int cbase = (wave * 4 + i) * 64;
      int c = cbase + lane;
      int row = c >> 3;
      int scc = (c & 7) ^ (row & 7);           // XOR swizzle of 16B chunks
      async16(A + (size_t)(tm + row) * K + k0 + scc * 8, &lA[cbase * 8]);
      async16(BT + (size_t)(tn + row) * K + k0 + scc * 8, &lB[cbase * 8]);
    }
    __syncthreads();
#pragma unroll
    for (int ks = 0; ks < 2; ks++) {
      bf16x8 af[4], bfr[4];
#pragma unroll
      for (int i = 0; i < 4; i++) {
        int ra = wm * 64 + i * 16 + l16;
        af[i] = ld8(&lA[ra * 64 + (((ks * 4 + quad) ^ (ra & 7)) << 3)]);
        int rb = wn * 64 + i * 16 + l16;
        bfr[i] = ld8(&lB[rb * 64 + (((ks * 4 + quad) ^ (rb & 7)) << 3)]);
      }
#pragma unroll
      for (int i = 0; i < 4; i++)
#pragma unroll
        for (int j = 0; j < 4; j++)
          acc[i][j] = __builtin_amdgcn_mfma_f32_16x16x32_bf16(af[i], bfr[j], acc[i][j], 0, 0, 0);
    }
  }

#pragma unroll
  for (int i = 0; i < 4; i++) {
    const int row0 = tm + wm * 64 + i * 16 + quad * 4;
#pragma unroll
    for (int j = 0; j < 4; j++) {
      const int col = tn + wn * 64 + j * 16 + l16;
      const float bv = bias[col];
#pragma unroll
      for (int r = 0; r < 4; r++) {
        float v = acc[i][j][r] + bv;
        if (RESID) v += resid[(size_t)(row0 + r) * N + col];
        if (RELU) v = fmaxf(v, 0.f);
        if (OUTBF) Cb[(size_t)(row0 + r) * N + col] = f2bf(v);
        else       Cf[(size_t)(row0 + r) * N + col] = v;
      }
    }
  }
}

// ---------- GEMM 128x64 tile (N=768: 768 blocks) ----------
template <int RESID, int RELU, int OUTBF, int RESBF>
__global__ __launch_bounds__(256, 4)
void gemm_bt64(const u16* __restrict__ A, const u16* __restrict__ BT,
               const float* __restrict__ bias, const float* __restrict__ residf,
               const u16* __restrict__ residb,
               float* __restrict__ Cf, u16* __restrict__ Cb, int N, int K) {
  __shared__ __align__(16) u16 lA[128 * 64];
  __shared__ __align__(16) u16 lB[64 * 64];
  const int tid = threadIdx.x;
  const int wave = tid >> 6, lane = tid & 63;
  const int quad = lane >> 4, l16 = lane & 15;
  const int wm = wave >> 1, wn = wave & 1;
  const int tm = blockIdx.y * 128, tn = blockIdx.x * 64;

  f32x4 acc[4][2] = {};

  for (int k0 = 0; k0 < K; k0 += 64) {
    __syncthreads();
#pragma unroll
    for (int i = 0; i < 4; i++) {
      int cbase = (wave * 4 + i) * 64;
      int c = cbase + lane;
      int row = c >> 3;
      int scc = (c & 7) ^ (row & 7);
      async16(A + (size_t)(tm + row) * K + k0 + scc * 8, &lA[cbase * 8]);
    }
#pragma unroll
    for (int i = 0; i < 2; i++) {
      int cbase = (wave * 2 + i) * 64;
      int c = cbase + lane;
      int row = c >> 3;
      int scc = (c & 7) ^ (row & 7);
      async16(BT + (size_t)(tn + row) * K + k0 + scc * 8, &lB[cbase * 8]);
    }
    __syncthreads();
#pragma unroll
    for (int ks = 0; ks < 2; ks++) {
      bf16x8 af[4], bfr[2];
#pragma unroll
      for (int i = 0; i < 4; i++) {
        int ra = wm * 64 + i * 16 + l16;
        af[i] = ld8(&lA[ra * 64 + (((ks * 4 + quad) ^ (ra & 7)) << 3)]);
      }
#pragma unroll
      for (int j = 0; j < 2; j++) {
        int rb = wn * 32 + j * 16 + l16;
        bfr[j] = ld8(&lB[rb * 64 + (((ks * 4 + quad) ^ (rb & 7)) << 3)]);
      }
#pragma unroll
      for (int i = 0; i < 4; i++)
#pragma unroll
        for (int j = 0; j < 2; j++)
          acc[i][j] = __builtin_amdgcn_mfma_f32_16x16x32_bf16(af[i], bfr[j], acc[i][j], 0, 0, 0);
    }
  }

#pragma unroll
  for (int i = 0; i < 4; i++) {
    const int row0 = tm + wm * 64 + i * 16 + quad * 4;
#pragma unroll
    for (int j = 0; j < 2; j++) {
      const int col = tn + wn * 32 + j * 16 + l16;
      const float bv = bias[col];
#pragma unroll
      for (int r = 0; r < 4; r++) {
        float v = acc[i][j][r] + bv;
        if (RESID) {
          if (RESBF) v += bf2f(residb[(size_t)(row0 + r) * N + col]);
          else       v += residf[(size_t)(row0 + r) * N + col];
        }
        if (RELU) v = fmaxf(v, 0.f);
        if (OUTBF) Cb[(size_t)(row0 + r) * N + col] = f2bf(v);
        else       Cf[(size_t)(row0 + r) * N + col] = v;
      }
    }
  }
}

// ---------- flash attention v8: split-K x2, 8 waves/block (16 waves/CU) ----------
// Fixed-shift softmax => P sums decompose linearly over k: partial O and l per
// key-half are summed by attn_combine. 512 threads/block keeps mi=2 operand
// amortization; LDS 79872 B -> 2 blocks/CU -> 4 waves/SIMD (was 2).
#define LKW 128   // lK row stride u16 (12 data chunks + 4 pad, swizzled)
#define LVW 64    // lV row stride u16 (exactly 8 chunks, swizzled)
#define LPP 44    // lP row stride u16
__global__ __launch_bounds__(512, 4)
void flash_attn(const u16* __restrict__ qkv, const u16* __restrict__ Vt,
                float* __restrict__ Opart, float* __restrict__ Lpart) {
  __shared__ __align__(16) u16 lK[2][64 * LKW];    // 2 x 16384 B
  __shared__ __align__(16) u16 lV[2][96 * LVW];    // 2 x 12288 B
  __shared__ __align__(16) u16 lP[8][32 * LPP];    // 22528 B   (total 79872 B)
  const int tid = threadIdx.x, wave = tid >> 6, lane = tid & 63;
  const int quad = lane >> 4, l16 = lane & 15;
  // XCD-aware decode: lin%8 = XCD; 4 heads/XCD; 8 q-blocks x 2 k-halves per head.
  const int lin = blockIdx.x;
  const int bh = (lin & 7) * 4 + ((lin >> 3) & 3);
  const int qb = (lin >> 5) & 7;
  const int kh = lin >> 8;                  // key half: 0 or 1
  const int b = bh >> 3, h = bh & 7;
  const int q0 = qb * 256 + wave * 32;
  const int k_lo = kh * 1024;
  const u16* Qp = qkv;
  const u16* KpB = qkv + 768 + (size_t)b * SEQ * QKVN + h * DK;
  const u16* VtB = Vt + (size_t)bh * DK * SEQ;
  const float cs = 0.10206207262f * LOG2E;  // (1/sqrt(96)) * log2(e)
  const float Ms = 16.0f * cs;              // fixed shift (folded)

  // Q fragments (32 rows per wave, reused across all K-tiles)
  bf16x8 qf[2][3];
#pragma unroll
  for (int mi = 0; mi < 2; mi++)
#pragma unroll
    for (int ks = 0; ks < 3; ks++)
      qf[mi][ks] = ld8(Qp + (size_t)(b * SEQ + q0 + mi * 16 + l16) * QKVN +
                       h * DK + ks * 32 + quad * 8);

  union { u16 u[8]; bf16x8 v; } onesu;
#pragma unroll
  for (int i = 0; i < 8; i++) onesu.u[i] = 0x3F80;  // bf16 1.0
  const bf16x8 onef = onesu.v;

  f32x4 of[2][6] = {};
  f32x4 l_acc[2] = {};
  u16* pw = lP[wave];

  // DMA one K/V tile into buf with 512 threads:
  // K = 1024 chunks (2/thread), V = 768 chunks (all threads + waves 0-3).
  auto stage = [&](int kt, int buf) {
#pragma unroll
    for (int i = 0; i < 2; i++) {
      int s = i * 512 + tid;
      int row = s >> 4;
      int c = (s & 15) ^ (row & 7);
      if (c > 11) c = 11;                    // pad slot: duplicate, never read
      async16(KpB + (size_t)(kt + row) * QKVN + c * 8,
              &lK[buf][(i * 512 + wave * 64) * 8]);
    }
    {
      int s = tid;
      int row = s >> 3;
      int c = (s & 7) ^ (row & 7);           // always < 8, no pad
      async16(VtB + (size_t)row * SEQ + kt + c * 8,
              &lV[buf][(wave * 64) * 8]);
    }
    if (wave < 4) {
      int s = 512 + tid;
      int row = s >> 3;
      int c = (s & 7) ^ (row & 7);
      async16(VtB + (size_t)row * SEQ + kt + c * 8,
              &lV[buf][(512 + wave * 64) * 8]);
    }
  };

  stage(k_lo, 0);
  int cur = 0;

  for (int kt = k_lo; kt < k_lo + 1024; kt += 64) {
    __syncthreads();  // drains DMA for buf[cur]; protects buf[cur^1] reuse
    if (kt + 64 < k_lo + 1024) stage(kt + 64, cur ^ 1);

    // scores = Q K^T
    f32x4 sc[2][4] = {};
#pragma unroll
    for (int ks = 0; ks < 3; ks++) {
      bf16x8 kb[4];
#pragma unroll
      for (int ni = 0; ni < 4; ni++)
        kb[ni] = ld8(&lK[cur][(ni * 16 + l16) * LKW +
                             (((ks * 4 + quad) ^ (l16 & 7)) << 3)]);
      __builtin_amdgcn_s_setprio(1);
#pragma unroll
      for (int mi = 0; mi < 2; mi++)
#pragma unroll
        for (int ni = 0; ni < 4; ni++)
          sc[mi][ni] = __builtin_amdgcn_mfma_f32_16x16x32_bf16(qf[mi][ks], kb[ni], sc[mi][ni], 0, 0, 0);
      __builtin_amdgcn_s_setprio(0);
    }

    // P = exp2(s*cs - Ms) -> bf16 via round-half-up (2 VALU), to per-wave LDS
#pragma unroll
    for (int mi = 0; mi < 2; mi++)
#pragma unroll
      for (int ni = 0; ni < 4; ni++)
#pragma unroll
        for (int r = 0; r < 4; r++) {
          float p = __builtin_amdgcn_exp2f(sc[mi][ni][r] * cs - Ms);
          union { float f; uint32_t u; } pu; pu.f = p;
          pw[(mi * 16 + quad * 4 + r) * LPP + ni * 16 + l16] =
              (u16)((pu.u + 0x8000u) >> 16);
        }

    // O += P @ V ; l += P @ 1
#pragma unroll
    for (int ks = 0; ks < 2; ks++) {
      bf16x8 pa[2];
#pragma unroll
      for (int mi = 0; mi < 2; mi++) {
        pa[mi] = ld8(&pw[(mi * 16 + l16) * LPP + ks * 32 + quad * 8]);
        l_acc[mi] = __builtin_amdgcn_mfma_f32_16x16x32_bf16(pa[mi], onef, l_acc[mi], 0, 0, 0);
      }
      __builtin_amdgcn_s_setprio(1);
#pragma unroll
      for (int j = 0; j < 6; j++) {
        bf16x8 vb = ld8(&lV[cur][(j * 16 + l16) * LVW +
                                 (((ks * 4 + quad) ^ (l16 & 7)) << 3)]);
#pragma unroll
        for (int mi = 0; mi < 2; mi++)
          of[mi][j] = __builtin_amdgcn_mfma_f32_16x16x32_bf16(pa[mi], vb, of[mi][j], 0, 0, 0);
      }
      __builtin_amdgcn_s_setprio(0);
    }
    cur ^= 1;
  }

  // epilogue: write unnormalized partial O (fp32) and partial l
#pragma unroll
  for (int mi = 0; mi < 2; mi++)
#pragma unroll
    for (int r = 0; r < 4; r++) {
      int qrow = q0 + mi * 16 + quad * 4 + r;
      size_t base = ((size_t)(kh * 32 + bh) * SEQ + qrow) * DK;
#pragma unroll
      for (int j = 0; j < 6; j++)
        Opart[base + j * 16 + l16] = of[mi][j][r];
      if (l16 == 0)
        Lpart[(size_t)(kh * 32 + bh) * SEQ + qrow] = l_acc[mi][r];
    }
}

// ---------- combine split-K partials: O = (O0+O1)/(l0+l1) -> bf16 ao ----------
__global__ __launch_bounds__(256)
void attn_combine(const float* __restrict__ Op, const float* __restrict__ Lp,
                  u16* __restrict__ Ob) {
  const int bh = blockIdx.y, b = bh >> 3, h = bh & 7;
  const int flat = blockIdx.x * 256 + threadIdx.x;   // 0..49151 (2048 q x 24)
  const int q = flat / 24, dq = (flat % 24) * 4;
  const size_t i0 = ((size_t)bh * SEQ + q) * DK + dq;
  const size_t i1 = ((size_t)(32 + bh) * SEQ + q) * DK + dq;
  float4 o0 = *(const float4*)(Op + i0);
  float4 o1 = *(const float4*)(Op + i1);
  float inv = 1.f / (Lp[(size_t)bh * SEQ + q] + Lp[(size_t)(32 + bh) * SEQ + q]);
  uint2 o;
  o.x = (unsigned)f2bf((o0.x + o1.x) * inv) |
        ((unsigned)f2bf((o0.y + o1.y) * inv) << 16);
  o.y = (unsigned)f2bf((o0.z + o1.z) * inv) |
        ((unsigned)f2bf((o0.w + o1.w) * inv) << 16);
  *(uint2*)(Ob + (size_t)(b * SEQ + q) * DM + h * DK + dq) = o;
}

// ---------- LayerNorm: out = LN(y); outf and/or outb optional ----------
__global__ __launch_bounds__(256)
void ln_kernel(const float* __restrict__ y, const float* __restrict__ g,
               const float* __restrict__ be, float* __restrict__ outf,
               u16* __restrict__ outb) {
  int row = blockIdx.x, t = threadIdx.x;
  const float* yr = y + (size_t)row * DM;
  float v[3], s = 0.f, s2 = 0.f;
#pragma unroll
  for (int i = 0; i < 3; i++) {
    v[i] = yr[t + i * 256];
    s += v[i];
    s2 += v[i] * v[i];
  }
#pragma unroll
  for (int m = 1; m < 64; m <<= 1) {
    s += __shfl_xor(s, m);
    s2 += __shfl_xor(s2, m);
  }
  __shared__ float red[2][4];
  int w = t >> 6;
  if ((t & 63) == 0) { red[0][w] = s; red[1][w] = s2; }
  __syncthreads();
  s = red[0][0] + red[0][1] + red[0][2] + red[0][3];
  s2 = red[1][0] + red[1][1] + red[1][2] + red[1][3];
  float mu = s * (1.f / DM);
  float var = s2 * (1.f / DM) - mu * mu;
  float rs = rsqrtf(var + 1e-5f);
#pragma unroll
  for (int i = 0; i < 3; i++) {
    int e = t + i * 256;
    float o = (v[i] - mu) * rs * g[e] + be[e];
    if (outf) outf[(size_t)row * DM + e] = o;
    if (outb) outb[(size_t)row * DM + e] = f2bf(o);
  }
}

// ---------- workspace layout (bytes) ----------
#define SZ_BF 12582912ull            // 8192*768*2
#define SZ_F  25165824ull            // 8192*768*4
#define O_XB   0ull                                  // x bf16; later attn_out
#define O_WT   (O_XB + SZ_BF)                        // qkv^T concat [2304][768] bf16; later Lpart
#define O_WOT  (O_WT + 3538944ull)
#define O_W1T  (O_WOT + 1179648ull)
#define O_W2T  (O_W1T + 3145728ull)
#define O_QKV  (O_W2T + 3145728ull)                  // [8192][2304] bf16; later x1b + h
#define O_VT   (O_QKV + 37748736ull)                 // [32][96][2048] bf16
#define O_Y    (O_VT + SZ_BF)                        // fp32 pre-LN buffer; Opart (2x25.2MB spans O_Y+O_X1F)
#define O_X1F  (O_Y + SZ_F)                          // second half of Opart
#define O_BIAS (O_X1F + SZ_F)                        // 2304 fp32 concat qkv bias

extern "C" void kernel_launch(void* const* d_in, const int* in_sizes, int n_in,
                              void* d_out, int out_size, void* d_ws, size_t ws_size,
                              hipStream_t stream) {
  const float* x   = (const float*)d_in[0];
  const float* Wq  = (const float*)d_in[1];
  const float* bq  = (const float*)d_in[2];
  const float* Wk  = (const float*)d_in[3];
  const float* bk  = (const float*)d_in[4];
  const float* Wv  = (const float*)d_in[5];
  const float* bv  = (const float*)d_in[6];
  const float* Wo  = (const float*)d_in[7];
  const float* bo  = (const float*)d_in[8];
  const float* g1  = (const float*)d_in[9];
  const float* be1 = (const float*)d_in[10];
  const float* W1  = (const float*)d_in[11];
  const float* b1  = (const float*)d_in[12];
  const float* W2  = (const float*)d_in[13];
  const float* b2  = (const float*)d_in[14];
  const float* g2  = (const float*)d_in[15];
  const float* be2 = (const float*)d_in[16];
  float* out = (float*)d_out;
  char* ws = (char*)d_ws;

  u16* xb    = (u16*)(ws + O_XB);
  u16* WT    = (u16*)(ws + O_WT);
  u16* WoT   = (u16*)(ws + O_WOT);
  u16* W1T   = (u16*)(ws + O_W1T);
  u16* W2T   = (u16*)(ws + O_W2T);
  u16* qkv   = (u16*)(ws + O_QKV);
  u16* vt    = (u16*)(ws + O_VT);
  float* y   = (float*)(ws + O_Y);
  float* bqkv = (float*)(ws + O_BIAS);
  u16* ao   = xb;                       // alias: xb dead after QKV GEMM
  u16* x1b  = qkv;                      // alias: qkv dead after attention
  u16* hbuf = qkv + (size_t)MTOK * DM;  // h [8192][2048] bf16
  float* opart = (float*)(ws + O_Y);    // split-K partial O: 2 x [32][2048][96] fp32
  float* lpart = (float*)(ws + O_WT);   // split-K partial l: 2 x [32][2048] fp32 (WT dead)

  // fused prep (one dispatch)
  prep<<<11529, 256, 0, stream>>>(x, xb, bq, bk, bv, bqkv,
                                  Wq, Wk, Wv, Wo, W1, W2,
                                  WT, WoT, W1T, W2T);

  // QKV projection (fused N=2304)
  gemm_bt<0, 0, 1><<<dim3(18, 64), 256, 0, stream>>>(xb, WT, bqkv, nullptr, nullptr, qkv, QKVN, DM);
  // V^T for PV B-operand
  transpose_v<<<dim3(64, 3, 32), dim3(32, 8), 0, stream>>>(qkv + 1536, vt);
  // attention: split-K x2, 512 blocks x 512 threads (16 waves/CU)
  flash_attn<<<512, 512, 0, stream>>>(qkv, vt, opart, lpart);
  // combine partials -> ao (bf16)
  attn_combine<<<dim3(192, 32), 256, 0, stream>>>(opart, lpart, ao);
  // out projection + residual(x fp32) -> y (fp32): N=768, 128x64 tiles
  gemm_bt64<1, 0, 0, 0><<<dim3(12, 64), 256, 0, stream>>>(ao, WoT, bo, x, nullptr, y, nullptr, DM, DM);
  // LN1 -> x1b (bf16 only; fp32 x1 round-trip eliminated)
  ln_kernel<<<8192, 256, 0, stream>>>(y, g1, be1, nullptr, x1b);
  // FFN1 + ReLU -> h (bf16)
  gemm_bt<0, 1, 1><<<dim3(16, 64), 256, 0, stream>>>(x1b, W1T, b1, nullptr, nullptr, hbuf, DFF, DM);
  // FFN2 + residual(x1b bf16) -> y (fp32): N=768, 128x64 tiles
  gemm_bt64<1, 0, 0, 1><<<dim3(12, 64), 256, 0, stream>>>(hbuf, W2T, b2, nullptr, x1b, y, nullptr, DM, DFF);
  // LN2 -> out
  ln_kernel<<<8192, 256, 0, stream>>>(y, g2, be2, out, nullptr);
}

// Round 2
// 384.720 us; speedup vs baseline: 1.0725x; 1.0725x over previous
//
#include <hip/hip_runtime.h>
#include <cstdint>
#include <cstddef>

typedef unsigned short u16;
typedef __bf16 bf16x8 __attribute__((ext_vector_type(8)));
typedef float f32x4 __attribute__((ext_vector_type(4)));

// ---------- constants ----------
#define BATCH 4
#define SEQ   2048
#define DM    768
#define NH    8
#define DK    96
#define DFF   2048
#define MTOK  8192          // BATCH*SEQ
#define QKVN  2304          // 3*DM
#define LOG2E 1.44269504088896340736f

// ---------- helpers ----------
__device__ __forceinline__ u16 f2bf(float f) {
  union { float f; uint32_t u; } v; v.f = f;
  return (u16)((v.u + 0x7fffu + ((v.u >> 16) & 1u)) >> 16);
}
__device__ __forceinline__ float bf2f(u16 b) {
  union { uint32_t u; float f; } v; v.u = (uint32_t)b << 16;
  return v.f;
}
__device__ __forceinline__ bf16x8 ld8(const u16* p) { return *(const bf16x8*)p; }
__device__ __forceinline__ void async16(const u16* g, u16* l) {
  __builtin_amdgcn_global_load_lds((const __attribute__((address_space(1))) void*)g,
                                   (__attribute__((address_space(3))) void*)l, 16, 0, 0);
}

// ---------- fused prep: cast_bf16 + concat3 + 6 weight transposes ----------
__global__ __launch_bounds__(256)
void prep(const float* __restrict__ x, u16* __restrict__ xb,
          const float* __restrict__ bq, const float* __restrict__ bk,
          const float* __restrict__ bv, float* __restrict__ bqkv,
          const float* __restrict__ Wq, const float* __restrict__ Wk,
          const float* __restrict__ Wv, const float* __restrict__ Wo,
          const float* __restrict__ W1, const float* __restrict__ W2,
          u16* __restrict__ WT, u16* __restrict__ WoT,
          u16* __restrict__ W1T, u16* __restrict__ W2T) {
  __shared__ float t[32][33];
  const int tid = threadIdx.x;
  int bid = blockIdx.x;

  if (bid < 6144) {                       // cast x (8192x768 fp32 -> bf16)
    size_t i = (size_t)bid * 1024 + tid * 4;
    float4 f = *(const float4*)(x + i);
    uint2 o;
    o.x = (unsigned)f2bf(f.x) | ((unsigned)f2bf(f.y) << 16);
    o.y = (unsigned)f2bf(f.z) | ((unsigned)f2bf(f.w) << 16);
    *(uint2*)(xb + i) = o;
    return;
  }
  if (bid < 6153) {                       // concat qkv bias (2304)
    int i = (bid - 6144) * 256 + tid;
    float v = (i < 768) ? bq[i] : (i < 1536) ? bk[i - 768] : bv[i - 1536];
    bqkv[i] = v;
    return;
  }
  bid -= 6153;
  const float* in; u16* out; int C, R, bx, by;
  if (bid < 576)       { in = Wq; out = WT;                 C = 768;  R = 768;  bx = bid % 24;          by = bid / 24; }
  else if (bid < 1152) { in = Wk; out = WT + 768 * 768;     C = 768;  R = 768;  bx = (bid - 576) % 24;  by = (bid - 576) / 24; }
  else if (bid < 1728) { in = Wv; out = WT + 2 * 768 * 768; C = 768;  R = 768;  bx = (bid - 1152) % 24; by = (bid - 1152) / 24; }
  else if (bid < 2304) { in = Wo; out = WoT;                C = 768;  R = 768;  bx = (bid - 1728) % 24; by = (bid - 1728) / 24; }
  else if (bid < 3840) { in = W1; out = W1T;                C = 2048; R = 768;  bx = (bid - 2304) % 64; by = (bid - 2304) / 64; }
  else                 { in = W2; out = W2T;                C = 768;  R = 2048; bx = (bid - 3840) % 24; by = (bid - 3840) / 24; }
  const int r0 = by * 32, c0 = bx * 32;
  const int tx = tid & 31, ty = tid >> 5;
#pragma unroll
  for (int i = 0; i < 4; i++)
    t[ty + i * 8][tx] = in[(size_t)(r0 + ty + i * 8) * C + c0 + tx];
  __syncthreads();
#pragma unroll
  for (int i = 0; i < 4; i++)
    out[(size_t)(c0 + ty + i * 8) * R + r0 + tx] = f2bf(t[tx][ty + i * 8]);
}

// v part of qkv (stride 2304) -> vt [B*H][96][2048] bf16
__global__ void transpose_v(const u16* __restrict__ v, u16* __restrict__ vt) {
  __shared__ u16 t[32][33];
  int bh = blockIdx.z, b = bh >> 3, h = bh & 7;
  int s0 = blockIdx.x * 32, d0 = blockIdx.y * 32;
  int tx = threadIdx.x, ty = threadIdx.y;
#pragma unroll
  for (int i = 0; i < 4; i++)
    t[ty + i * 8][tx] = v[(size_t)(b * SEQ + s0 + ty + i * 8) * QKVN + h * DK + d0 + tx];
  __syncthreads();
#pragma unroll
  for (int i = 0; i < 4; i++)
    vt[(size_t)(bh * DK + d0 + ty + i * 8) * SEQ + s0 + tx] = t[tx][ty + i * 8];
}

// ---------- GEMM: C[M,N] = A[M,K] @ BT[N,K]^T + bias (+resid)(+relu) ----------
template <int RESID, int RELU, int OUTBF>
__global__ __launch_bounds__(256, 4)
void gemm_bt(const u16* __restrict__ A, const u16* __restrict__ BT,
             const float* __restrict__ bias, const float* __restrict__ resid,
             float* __restrict__ Cf, u16* __restrict__ Cb, int N, int K) {
  __shared__ __align__(16) u16 lA[128 * 64];
  __shared__ __align__(16) u16 lB[128 * 64];
  const int tid = threadIdx.x;
  const int wave = tid >> 6, lane = tid & 63;
  const int quad = lane >> 4, l16 = lane & 15;
  const int wm = wave >> 1, wn = wave & 1;
  const int tm = blockIdx.y * 128, tn = blockIdx.x * 128;

  f32x4 acc[4][4] = {};

  for (int k0 = 0; k0 < K; k0 += 64) {
    __syncthreads();
#pragma unroll
    for (int i = 0; i < 4; i++) {
      int cbase = (wave * 4 + i) * 64;
      int c = cbase + lane;
      int row = c >> 3;
      int scc = (c & 7) ^ (row & 7);           // XOR swizzle of 16B chunks
      async16(A + (size_t)(tm + row) * K + k0 + scc * 8, &lA[cbase * 8]);
      async16(BT + (size_t)(tn + row) * K + k0 + scc * 8, &lB[cbase * 8]);
    }
    __syncthreads();
#pragma unroll
    for (int ks = 0; ks < 2; ks++) {
      bf16x8 af[4], bfr[4];
#pragma unroll
      for (int i = 0; i < 4; i++) {
        int ra = wm * 64 + i * 16 + l16;
        af[i] = ld8(&lA[ra * 64 + (((ks * 4 + quad) ^ (ra & 7)) << 3)]);
        int rb = wn * 64 + i * 16 + l16;
        bfr[i] = ld8(&lB[rb * 64 + (((ks * 4 + quad) ^ (rb & 7)) << 3)]);
      }
#pragma unroll
      for (int i = 0; i < 4; i++)
#pragma unroll
        for (int j = 0; j < 4; j++)
          acc[i][j] = __builtin_amdgcn_mfma_f32_16x16x32_bf16(af[i], bfr[j], acc[i][j], 0, 0, 0);
    }
  }

#pragma unroll
  for (int i = 0; i < 4; i++) {
    const int row0 = tm + wm * 64 + i * 16 + quad * 4;
#pragma unroll
    for (int j = 0; j < 4; j++) {
      const int col = tn + wn * 64 + j * 16 + l16;
      const float bv = bias[col];
#pragma unroll
      for (int r = 0; r < 4; r++) {
        float v = acc[i][j][r] + bv;
        if (RESID) v += resid[(size_t)(row0 + r) * N + col];
        if (RELU) v = fmaxf(v, 0.f);
        if (OUTBF) Cb[(size_t)(row0 + r) * N + col] = f2bf(v);
        else       Cf[(size_t)(row0 + r) * N + col] = v;
      }
    }
  }
}

// ---------- GEMM 128x64 tile (N=768: 768 blocks) ----------
template <int RESID, int RELU, int OUTBF, int RESBF>
__global__ __launch_bounds__(256, 4)
void gemm_bt64(const u16* __restrict__ A, const u16* __restrict__ BT,
               const float* __restrict__ bias, const float* __restrict__ residf,
               const u16* __restrict__ residb,
               float* __restrict__ Cf, u16* __restrict__ Cb, int N, int K) {
  __shared__ __align__(16) u16 lA[128 * 64];
  __shared__ __align__(16) u16 lB[64 * 64];
  const int tid = threadIdx.x;
  const int wave = tid >> 6, lane = tid & 63;
  const int quad = lane >> 4, l16 = lane & 15;
  const int wm = wave >> 1, wn = wave & 1;
  const int tm = blockIdx.y * 128, tn = blockIdx.x * 64;

  f32x4 acc[4][2] = {};

  for (int k0 = 0; k0 < K; k0 += 64) {
    __syncthreads();
#pragma unroll
    for (int i = 0; i < 4; i++) {
      int cbase = (wave * 4 + i) * 64;
      int c = cbase + lane;
      int row = c >> 3;
      int scc = (c & 7) ^ (row & 7);
      async16(A + (size_t)(tm + row) * K + k0 + scc * 8, &lA[cbase * 8]);
    }
#pragma unroll
    for (int i = 0; i < 2; i++) {
      int cbase = (wave * 2 + i) * 64;
      int c = cbase + lane;
      int row = c >> 3;
      int scc = (c & 7) ^ (row & 7);
      async16(BT + (size_t)(tn + row) * K + k0 + scc * 8, &lB[cbase * 8]);
    }
    __syncthreads();
#pragma unroll
    for (int ks = 0; ks < 2; ks++) {
      bf16x8 af[4], bfr[2];
#pragma unroll
      for (int i = 0; i < 4; i++) {
        int ra = wm * 64 + i * 16 + l16;
        af[i] = ld8(&lA[ra * 64 + (((ks * 4 + quad) ^ (ra & 7)) << 3)]);
      }
#pragma unroll
      for (int j = 0; j < 2; j++) {
        int rb = wn * 32 + j * 16 + l16;
        bfr[j] = ld8(&lB[rb * 64 + (((ks * 4 + quad) ^ (rb & 7)) << 3)]);
      }
#pragma unroll
      for (int i = 0; i < 4; i++)
#pragma unroll
        for (int j = 0; j < 2; j++)
          acc[i][j] = __builtin_amdgcn_mfma_f32_16x16x32_bf16(af[i], bfr[j], acc[i][j], 0, 0, 0);
    }
  }

#pragma unroll
  for (int i = 0; i < 4; i++) {
    const int row0 = tm + wm * 64 + i * 16 + quad * 4;
#pragma unroll
    for (int j = 0; j < 2; j++) {
      const int col = tn + wn * 32 + j * 16 + l16;
      const float bv = bias[col];
#pragma unroll
      for (int r = 0; r < 4; r++) {
        float v = acc[i][j][r] + bv;
        if (RESID) {
          if (RESBF) v += bf2f(residb[(size_t)(row0 + r) * N + col]);
          else       v += residf[(size_t)(row0 + r) * N + col];
        }
        if (RELU) v = fmaxf(v, 0.f);
        if (OUTBF) Cb[(size_t)(row0 + r) * N + col] = f2bf(v);
        else       Cf[(size_t)(row0 + r) * N + col] = v;
      }
    }
  }
}

// ---------- flash attention v9: 8 waves x 16 q-rows, no split-K ----------
// Round-1 post-mortem: 512-thr/mi=2 spilled (VGPR cap 128 < ~145 peak live ->
// FETCH 18->172MB scratch traffic). mi=1 cuts persistent state to ~40 regs
// (of[6]=24 + qf[3]=12 + l_acc=4); peak ~100 <= 128 -> no spill, and the
// occupancy mechanism (2 blocks/CU x 8 waves = 4 waves/SIMD, was 2) is kept.
// No split-K: grid 512 = 32 bh x 16 qb covers full 2048 keys per block,
// direct bf16 output, no partial-O HBM round-trip.
#define LKW 128   // lK row stride u16 (12 data chunks + 4 pad, swizzled)
#define LVW 64    // lV row stride u16 (exactly 8 chunks, swizzled)
#define LPP 44    // lP row stride u16
__global__ __launch_bounds__(512, 4)
void flash_attn(const u16* __restrict__ qkv, const u16* __restrict__ Vt,
                u16* __restrict__ Ob) {
  __shared__ __align__(16) u16 lK[2][64 * LKW];    // 2 x 16384 B
  __shared__ __align__(16) u16 lV[2][96 * LVW];    // 2 x 12288 B
  __shared__ __align__(16) u16 lP[8][16 * LPP];    // 11264 B   (total 68608 B)
  const int tid = threadIdx.x, wave = tid >> 6, lane = tid & 63;
  const int quad = lane >> 4, l16 = lane & 15;
  // XCD-aware decode: lin%8 = XCD; 4 heads/XCD; 16 q-blocks per head.
  const int lin = blockIdx.x;
  const int bh = (lin & 7) * 4 + ((lin >> 3) & 3);
  const int qb = lin >> 5;
  const int b = bh >> 3, h = bh & 7;
  const int q0 = qb * 128 + wave * 16;
  const u16* Qp = qkv;
  const u16* KpB = qkv + 768 + (size_t)b * SEQ * QKVN + h * DK;
  const u16* VtB = Vt + (size_t)bh * DK * SEQ;
  const float cs = 0.10206207262f * LOG2E;  // (1/sqrt(96)) * log2(e)
  const float Ms = 16.0f * cs;              // fixed shift (folded)

  // Q fragments (16 rows per wave, reused across all K-tiles)
  bf16x8 qf[3];
#pragma unroll
  for (int ks = 0; ks < 3; ks++)
    qf[ks] = ld8(Qp + (size_t)(b * SEQ + q0 + l16) * QKVN +
                 h * DK + ks * 32 + quad * 8);

  union { u16 u[8]; bf16x8 v; } onesu;
#pragma unroll
  for (int i = 0; i < 8; i++) onesu.u[i] = 0x3F80;  // bf16 1.0
  const bf16x8 onef = onesu.v;

  f32x4 of[6] = {};
  f32x4 l_acc = {};
  u16* pw = lP[wave];

  // DMA one K/V tile into buf with 512 threads:
  // K = 1024 chunks (2/thread), V = 768 chunks (all threads + waves 0-3).
  auto stage = [&](int kt, int buf) {
#pragma unroll
    for (int i = 0; i < 2; i++) {
      int s = i * 512 + tid;
      int row = s >> 4;
      int c = (s & 15) ^ (row & 7);
      if (c > 11) c = 11;                    // pad slot: duplicate, never read
      async16(KpB + (size_t)(kt + row) * QKVN + c * 8,
              &lK[buf][(i * 512 + wave * 64) * 8]);
    }
    {
      int s = tid;
      int row = s >> 3;
      int c = (s & 7) ^ (row & 7);           // always < 8, no pad
      async16(VtB + (size_t)row * SEQ + kt + c * 8,
              &lV[buf][(wave * 64) * 8]);
    }
    if (wave < 4) {
      int s = 512 + tid;
      int row = s >> 3;
      int c = (s & 7) ^ (row & 7);
      async16(VtB + (size_t)row * SEQ + kt + c * 8,
              &lV[buf][(512 + wave * 64) * 8]);
    }
  };

  stage(0, 0);
  int cur = 0;

  for (int kt = 0; kt < SEQ; kt += 64) {
    __syncthreads();  // drains DMA for buf[cur]; protects buf[cur^1] reuse
    if (kt + 64 < SEQ) stage(kt + 64, cur ^ 1);

    // scores = Q K^T  (16 q-rows x 64 keys per wave)
    f32x4 sc[4] = {};
#pragma unroll
    for (int ks = 0; ks < 3; ks++) {
      bf16x8 kb[4];
#pragma unroll
      for (int ni = 0; ni < 4; ni++)
        kb[ni] = ld8(&lK[cur][(ni * 16 + l16) * LKW +
                             (((ks * 4 + quad) ^ (l16 & 7)) << 3)]);
      __builtin_amdgcn_s_setprio(1);
#pragma unroll
      for (int ni = 0; ni < 4; ni++)
        sc[ni] = __builtin_amdgcn_mfma_f32_16x16x32_bf16(qf[ks], kb[ni], sc[ni], 0, 0, 0);
      __builtin_amdgcn_s_setprio(0);
    }

    // P = exp2(s*cs - Ms) -> bf16 via round-half-up (2 VALU), to per-wave LDS
#pragma unroll
    for (int ni = 0; ni < 4; ni++)
#pragma unroll
      for (int r = 0; r < 4; r++) {
        float p = __builtin_amdgcn_exp2f(sc[ni][r] * cs - Ms);
        union { float f; uint32_t u; } pu; pu.f = p;
        pw[(quad * 4 + r) * LPP + ni * 16 + l16] =
            (u16)((pu.u + 0x8000u) >> 16);
      }

    // O += P @ V ; l += P @ 1
#pragma unroll
    for (int ks = 0; ks < 2; ks++) {
      bf16x8 pa = ld8(&pw[l16 * LPP + ks * 32 + quad * 8]);
      l_acc = __builtin_amdgcn_mfma_f32_16x16x32_bf16(pa, onef, l_acc, 0, 0, 0);
      __builtin_amdgcn_s_setprio(1);
#pragma unroll
      for (int j = 0; j < 6; j++) {
        bf16x8 vb = ld8(&lV[cur][(j * 16 + l16) * LVW +
                                 (((ks * 4 + quad) ^ (l16 & 7)) << 3)]);
        of[j] = __builtin_amdgcn_mfma_f32_16x16x32_bf16(pa, vb, of[j], 0, 0, 0);
      }
      __builtin_amdgcn_s_setprio(0);
    }
    cur ^= 1;
  }

  // epilogue: O / l -> attn_out bf16 [tok][DM]
#pragma unroll
  for (int r = 0; r < 4; r++) {
    float inv = 1.f / l_acc[r];
    int qrow = q0 + quad * 4 + r;
#pragma unroll
    for (int j = 0; j < 6; j++)
      Ob[(size_t)(b * SEQ + qrow) * DM + h * DK + j * 16 + l16] = f2bf(of[j][r] * inv);
  }
}

// ---------- LayerNorm: out = LN(y); outf and/or outb optional ----------
__global__ __launch_bounds__(256)
void ln_kernel(const float* __restrict__ y, const float* __restrict__ g,
               const float* __restrict__ be, float* __restrict__ outf,
               u16* __restrict__ outb) {
  int row = blockIdx.x, t = threadIdx.x;
  const float* yr = y + (size_t)row * DM;
  float v[3], s = 0.f, s2 = 0.f;
#pragma unroll
  for (int i = 0; i < 3; i++) {
    v[i] = yr[t + i * 256];
    s += v[i];
    s2 += v[i] * v[i];
  }
#pragma unroll
  for (int m = 1; m < 64; m <<= 1) {
    s += __shfl_xor(s, m);
    s2 += __shfl_xor(s2, m);
  }
  __shared__ float red[2][4];
  int w = t >> 6;
  if ((t & 63) == 0) { red[0][w] = s; red[1][w] = s2; }
  __syncthreads();
  s = red[0][0] + red[0][1] + red[0][2] + red[0][3];
  s2 = red[1][0] + red[1][1] + red[1][2] + red[1][3];
  float mu = s * (1.f / DM);
  float var = s2 * (1.f / DM) - mu * mu;
  float rs = rsqrtf(var + 1e-5f);
#pragma unroll
  for (int i = 0; i < 3; i++) {
    int e = t + i * 256;
    float o = (v[i] - mu) * rs * g[e] + be[e];
    if (outf) outf[(size_t)row * DM + e] = o;
    if (outb) outb[(size_t)row * DM + e] = f2bf(o);
  }
}

// ---------- workspace layout (bytes) ----------
#define SZ_BF 12582912ull            // 8192*768*2
#define SZ_F  25165824ull            // 8192*768*4
#define O_XB   0ull                                  // x bf16; later attn_out
#define O_WT   (O_XB + SZ_BF)                        // qkv^T concat [2304][768] bf16
#define O_WOT  (O_WT + 3538944ull)
#define O_W1T  (O_WOT + 1179648ull)
#define O_W2T  (O_W1T + 3145728ull)
#define O_QKV  (O_W2T + 3145728ull)                  // [8192][2304] bf16; later x1b + h
#define O_VT   (O_QKV + 37748736ull)                 // [32][96][2048] bf16
#define O_Y    (O_VT + SZ_BF)                        // fp32 pre-LN buffer
#define O_X1F  (O_Y + SZ_F)                          // (unused now)
#define O_BIAS (O_X1F + SZ_F)                        // 2304 fp32 concat qkv bias

extern "C" void kernel_launch(void* const* d_in, const int* in_sizes, int n_in,
                              void* d_out, int out_size, void* d_ws, size_t ws_size,
                              hipStream_t stream) {
  const float* x   = (const float*)d_in[0];
  const float* Wq  = (const float*)d_in[1];
  const float* bq  = (const float*)d_in[2];
  const float* Wk  = (const float*)d_in[3];
  const float* bk  = (const float*)d_in[4];
  const float* Wv  = (const float*)d_in[5];
  const float* bv  = (const float*)d_in[6];
  const float* Wo  = (const float*)d_in[7];
  const float* bo  = (const float*)d_in[8];
  const float* g1  = (const float*)d_in[9];
  const float* be1 = (const float*)d_in[10];
  const float* W1  = (const float*)d_in[11];
  const float* b1  = (const float*)d_in[12];
  const float* W2  = (const float*)d_in[13];
  const float* b2  = (const float*)d_in[14];
  const float* g2  = (const float*)d_in[15];
  const float* be2 = (const float*)d_in[16];
  float* out = (float*)d_out;
  char* ws = (char*)d_ws;

  u16* xb    = (u16*)(ws + O_XB);
  u16* WT    = (u16*)(ws + O_WT);
  u16* WoT   = (u16*)(ws + O_WOT);
  u16* W1T   = (u16*)(ws + O_W1T);
  u16* W2T   = (u16*)(ws + O_W2T);
  u16* qkv   = (u16*)(ws + O_QKV);
  u16* vt    = (u16*)(ws + O_VT);
  float* y   = (float*)(ws + O_Y);
  float* bqkv = (float*)(ws + O_BIAS);
  u16* ao   = xb;                       // alias: xb dead after QKV GEMM
  u16* x1b  = qkv;                      // alias: qkv dead after attention
  u16* hbuf = qkv + (size_t)MTOK * DM;  // h [8192][2048] bf16

  // fused prep (one dispatch)
  prep<<<11529, 256, 0, stream>>>(x, xb, bq, bk, bv, bqkv,
                                  Wq, Wk, Wv, Wo, W1, W2,
                                  WT, WoT, W1T, W2T);

  // QKV projection (fused N=2304)
  gemm_bt<0, 0, 1><<<dim3(18, 64), 256, 0, stream>>>(xb, WT, bqkv, nullptr, nullptr, qkv, QKVN, DM);
  // V^T for PV B-operand
  transpose_v<<<dim3(64, 3, 32), dim3(32, 8), 0, stream>>>(qkv + 1536, vt);
  // attention: 512 blocks x 512 threads (8 waves x 16 q-rows, 2 blocks/CU)
  flash_attn<<<512, 512, 0, stream>>>(qkv, vt, ao);
  // out projection + residual(x fp32) -> y (fp32): N=768, 128x64 tiles
  gemm_bt64<1, 0, 0, 0><<<dim3(12, 64), 256, 0, stream>>>(ao, WoT, bo, x, nullptr, y, nullptr, DM, DM);
  // LN1 -> x1b (bf16 only; fp32 x1 round-trip eliminated)
  ln_kernel<<<8192, 256, 0, stream>>>(y, g1, be1, nullptr, x1b);
  // FFN1 + ReLU -> h (bf16)
  gemm_bt<0, 1, 1><<<dim3(16, 64), 256, 0, stream>>>(x1b, W1T, b1, nullptr, nullptr, hbuf, DFF, DM);
  // FFN2 + residual(x1b bf16) -> y (fp32): N=768, 128x64 tiles
  gemm_bt64<1, 0, 0, 1><<<dim3(12, 64), 256, 0, stream>>>(hbuf, W2T, b2, nullptr, x1b, y, nullptr, DM, DFF);
  // LN2 -> out
  ln_kernel<<<8192, 256, 0, stream>>>(y, g2, be2, out, nullptr);
}

// Round 3
// 345.284 us; speedup vs baseline: 1.1950x; 1.1142x over previous
//
#include <hip/hip_runtime.h>
#include <cstdint>
#include <cstddef>

typedef unsigned short u16;
typedef __bf16 bf16x8 __attribute__((ext_vector_type(8)));
typedef float f32x4 __attribute__((ext_vector_type(4)));
typedef float f32x16 __attribute__((ext_vector_type(16)));

// ---------- constants ----------
#define BATCH 4
#define SEQ   2048
#define DM    768
#define NH    8
#define DK    96
#define DFF   2048
#define MTOK  8192          // BATCH*SEQ
#define QKVN  2304          // 3*DM
#define LOG2E 1.44269504088896340736f

// ---------- helpers ----------
__device__ __forceinline__ u16 f2bf(float f) {
  union { float f; uint32_t u; } v; v.f = f;
  return (u16)((v.u + 0x7fffu + ((v.u >> 16) & 1u)) >> 16);
}
__device__ __forceinline__ float bf2f(u16 b) {
  union { uint32_t u; float f; } v; v.u = (uint32_t)b << 16;
  return v.f;
}
__device__ __forceinline__ bf16x8 ld8(const u16* p) { return *(const bf16x8*)p; }
__device__ __forceinline__ void async16(const u16* g, u16* l) {
  __builtin_amdgcn_global_load_lds((const __attribute__((address_space(1))) void*)g,
                                   (__attribute__((address_space(3))) void*)l, 16, 0, 0);
}

// ---------- fused prep: cast_bf16 + concat3 + 6 weight transposes ----------
__global__ __launch_bounds__(256)
void prep(const float* __restrict__ x, u16* __restrict__ xb,
          const float* __restrict__ bq, const float* __restrict__ bk,
          const float* __restrict__ bv, float* __restrict__ bqkv,
          const float* __restrict__ Wq, const float* __restrict__ Wk,
          const float* __restrict__ Wv, const float* __restrict__ Wo,
          const float* __restrict__ W1, const float* __restrict__ W2,
          u16* __restrict__ WT, u16* __restrict__ WoT,
          u16* __restrict__ W1T, u16* __restrict__ W2T) {
  __shared__ float t[32][33];
  const int tid = threadIdx.x;
  int bid = blockIdx.x;

  if (bid < 6144) {                       // cast x (8192x768 fp32 -> bf16)
    size_t i = (size_t)bid * 1024 + tid * 4;
    float4 f = *(const float4*)(x + i);
    uint2 o;
    o.x = (unsigned)f2bf(f.x) | ((unsigned)f2bf(f.y) << 16);
    o.y = (unsigned)f2bf(f.z) | ((unsigned)f2bf(f.w) << 16);
    *(uint2*)(xb + i) = o;
    return;
  }
  if (bid < 6153) {                       // concat qkv bias (2304)
    int i = (bid - 6144) * 256 + tid;
    float v = (i < 768) ? bq[i] : (i < 1536) ? bk[i - 768] : bv[i - 1536];
    bqkv[i] = v;
    return;
  }
  bid -= 6153;
  const float* in; u16* out; int C, R, bx, by;
  if (bid < 576)       { in = Wq; out = WT;                 C = 768;  R = 768;  bx = bid % 24;          by = bid / 24; }
  else if (bid < 1152) { in = Wk; out = WT + 768 * 768;     C = 768;  R = 768;  bx = (bid - 576) % 24;  by = (bid - 576) / 24; }
  else if (bid < 1728) { in = Wv; out = WT + 2 * 768 * 768; C = 768;  R = 768;  bx = (bid - 1152) % 24; by = (bid - 1152) / 24; }
  else if (bid < 2304) { in = Wo; out = WoT;                C = 768;  R = 768;  bx = (bid - 1728) % 24; by = (bid - 1728) / 24; }
  else if (bid < 3840) { in = W1; out = W1T;                C = 2048; R = 768;  bx = (bid - 2304) % 64; by = (bid - 2304) / 64; }
  else                 { in = W2; out = W2T;                C = 768;  R = 2048; bx = (bid - 3840) % 24; by = (bid - 3840) / 24; }
  const int r0 = by * 32, c0 = bx * 32;
  const int tx = tid & 31, ty = tid >> 5;
#pragma unroll
  for (int i = 0; i < 4; i++)
    t[ty + i * 8][tx] = in[(size_t)(r0 + ty + i * 8) * C + c0 + tx];
  __syncthreads();
#pragma unroll
  for (int i = 0; i < 4; i++)
    out[(size_t)(c0 + ty + i * 8) * R + r0 + tx] = f2bf(t[tx][ty + i * 8]);
}

// v part of qkv (stride 2304) -> vt [B*H][96][2048] bf16
__global__ void transpose_v(const u16* __restrict__ v, u16* __restrict__ vt) {
  __shared__ u16 t[32][33];
  int bh = blockIdx.z, b = bh >> 3, h = bh & 7;
  int s0 = blockIdx.x * 32, d0 = blockIdx.y * 32;
  int tx = threadIdx.x, ty = threadIdx.y;
#pragma unroll
  for (int i = 0; i < 4; i++)
    t[ty + i * 8][tx] = v[(size_t)(b * SEQ + s0 + ty + i * 8) * QKVN + h * DK + d0 + tx];
  __syncthreads();
#pragma unroll
  for (int i = 0; i < 4; i++)
    vt[(size_t)(bh * DK + d0 + ty + i * 8) * SEQ + s0 + tx] = t[tx][ty + i * 8];
}

// ---------- GEMM: C[M,N] = A[M,K] @ BT[N,K]^T + bias (+resid)(+relu) ----------
template <int RESID, int RELU, int OUTBF>
__global__ __launch_bounds__(256, 4)
void gemm_bt(const u16* __restrict__ A, const u16* __restrict__ BT,
             const float* __restrict__ bias, const float* __restrict__ resid,
             float* __restrict__ Cf, u16* __restrict__ Cb, int N, int K) {
  __shared__ __align__(16) u16 lA[128 * 64];
  __shared__ __align__(16) u16 lB[128 * 64];
  const int tid = threadIdx.x;
  const int wave = tid >> 6, lane = tid & 63;
  const int quad = lane >> 4, l16 = lane & 15;
  const int wm = wave >> 1, wn = wave & 1;
  const int tm = blockIdx.y * 128, tn = blockIdx.x * 128;

  f32x4 acc[4][4] = {};

  for (int k0 = 0; k0 < K; k0 += 64) {
    __syncthreads();
#pragma unroll
    for (int i = 0; i < 4; i++) {
      int cbase = (wave * 4 + i) * 64;
      int c = cbase + lane;
      int row = c >> 3;
      int scc = (c & 7) ^ (row & 7);           // XOR swizzle of 16B chunks
      async16(A + (size_t)(tm + row) * K + k0 + scc * 8, &lA[cbase * 8]);
      async16(BT + (size_t)(tn + row) * K + k0 + scc * 8, &lB[cbase * 8]);
    }
    __syncthreads();
#pragma unroll
    for (int ks = 0; ks < 2; ks++) {
      bf16x8 af[4], bfr[4];
#pragma unroll
      for (int i = 0; i < 4; i++) {
        int ra = wm * 64 + i * 16 + l16;
        af[i] = ld8(&lA[ra * 64 + (((ks * 4 + quad) ^ (ra & 7)) << 3)]);
        int rb = wn * 64 + i * 16 + l16;
        bfr[i] = ld8(&lB[rb * 64 + (((ks * 4 + quad) ^ (rb & 7)) << 3)]);
      }
#pragma unroll
      for (int i = 0; i < 4; i++)
#pragma unroll
        for (int j = 0; j < 4; j++)
          acc[i][j] = __builtin_amdgcn_mfma_f32_16x16x32_bf16(af[i], bfr[j], acc[i][j], 0, 0, 0);
    }
  }

#pragma unroll
  for (int i = 0; i < 4; i++) {
    const int row0 = tm + wm * 64 + i * 16 + quad * 4;
#pragma unroll
    for (int j = 0; j < 4; j++) {
      const int col = tn + wn * 64 + j * 16 + l16;
      const float bv = bias[col];
#pragma unroll
      for (int r = 0; r < 4; r++) {
        float v = acc[i][j][r] + bv;
        if (RESID) v += resid[(size_t)(row0 + r) * N + col];
        if (RELU) v = fmaxf(v, 0.f);
        if (OUTBF) Cb[(size_t)(row0 + r) * N + col] = f2bf(v);
        else       Cf[(size_t)(row0 + r) * N + col] = v;
      }
    }
  }
}

// ---------- GEMM 128x64 tile (N=768: 768 blocks) ----------
template <int RESID, int RELU, int OUTBF, int RESBF>
__global__ __launch_bounds__(256, 4)
void gemm_bt64(const u16* __restrict__ A, const u16* __restrict__ BT,
               const float* __restrict__ bias, const float* __restrict__ residf,
               const u16* __restrict__ residb,
               float* __restrict__ Cf, u16* __restrict__ Cb, int N, int K) {
  __shared__ __align__(16) u16 lA[128 * 64];
  __shared__ __align__(16) u16 lB[64 * 64];
  const int tid = threadIdx.x;
  const int wave = tid >> 6, lane = tid & 63;
  const int quad = lane >> 4, l16 = lane & 15;
  const int wm = wave >> 1, wn = wave & 1;
  const int tm = blockIdx.y * 128, tn = blockIdx.x * 64;

  f32x4 acc[4][2] = {};

  for (int k0 = 0; k0 < K; k0 += 64) {
    __syncthreads();
#pragma unroll
    for (int i = 0; i < 4; i++) {
      int cbase = (wave * 4 + i) * 64;
      int c = cbase + lane;
      int row = c >> 3;
      int scc = (c & 7) ^ (row & 7);
      async16(A + (size_t)(tm + row) * K + k0 + scc * 8, &lA[cbase * 8]);
    }
#pragma unroll
    for (int i = 0; i < 2; i++) {
      int cbase = (wave * 2 + i) * 64;
      int c = cbase + lane;
      int row = c >> 3;
      int scc = (c & 7) ^ (row & 7);
      async16(BT + (size_t)(tn + row) * K + k0 + scc * 8, &lB[cbase * 8]);
    }
    __syncthreads();
#pragma unroll
    for (int ks = 0; ks < 2; ks++) {
      bf16x8 af[4], bfr[2];
#pragma unroll
      for (int i = 0; i < 4; i++) {
        int ra = wm * 64 + i * 16 + l16;
        af[i] = ld8(&lA[ra * 64 + (((ks * 4 + quad) ^ (ra & 7)) << 3)]);
      }
#pragma unroll
      for (int j = 0; j < 2; j++) {
        int rb = wn * 32 + j * 16 + l16;
        bfr[j] = ld8(&lB[rb * 64 + (((ks * 4 + quad) ^ (rb & 7)) << 3)]);
      }
#pragma unroll
      for (int i = 0; i < 4; i++)
#pragma unroll
        for (int j = 0; j < 2; j++)
          acc[i][j] = __builtin_amdgcn_mfma_f32_16x16x32_bf16(af[i], bfr[j], acc[i][j], 0, 0, 0);
    }
  }

#pragma unroll
  for (int i = 0; i < 4; i++) {
    const int row0 = tm + wm * 64 + i * 16 + quad * 4;
#pragma unroll
    for (int j = 0; j < 2; j++) {
      const int col = tn + wn * 32 + j * 16 + l16;
      const float bv = bias[col];
#pragma unroll
      for (int r = 0; r < 4; r++) {
        float v = acc[i][j][r] + bv;
        if (RESID) {
          if (RESBF) v += bf2f(residb[(size_t)(row0 + r) * N + col]);
          else       v += residf[(size_t)(row0 + r) * N + col];
        }
        if (RELU) v = fmaxf(v, 0.f);
        if (OUTBF) Cb[(size_t)(row0 + r) * N + col] = f2bf(v);
        else       Cf[(size_t)(row0 + r) * N + col] = v;
      }
    }
  }
}

// ---------- flash attention v10: 32x32 MFMA, in-register softmax ----------
// Round-2 post-mortem: LDS-pipe-bound (416 b128 reads + P round-trip per
// CU-iter ~6800 of 7900 cyc). Fix: swapped-operand 32x32x16 MFMAs.
//   QK^T: sc = mfma32(Kfrag, Q^T frag) -> lane holds S[keys][q=lane&31].
//   softmax: in-register exp2; l as per-lane scalar (each lane owns one q).
//   pack:   v_cvt_pk_bf16_f32 x16 + v_permlane32_swap_b32 x8 -> PV B-frags.
//   PV:     O^T = mfma32(V^T frag, P^T frag). vt is [dk][seq] -> direct ld8.
// Per wave per 64-key tile: 24 ds_read_b128, 0 LDS writes (was 26+16 for
// half the q-rows). lP deleted: LDS 57344 B -> 2 blocks/CU, 8 waves/CU.
#define LKW 128   // lK row stride u16 (12 data chunks + 4 pad, swizzled)
#define LVW 64    // lV row stride u16 (exactly 8 chunks, swizzled)

// pack one 16-key slice (8 f32 score regs) into one PV B-fragment:
// B-frag key j (local) lives at half h lanes as keys 8h+j; sources:
//   u0=cvtpk(p0,p1) u1=cvtpk(p2,p3) u2=cvtpk(p4,p5) u3=cvtpk(p6,p7)
//   swap(u2,u0): u0 -> W0(keys 0,1), u2 -> W2(keys 4,5)
//   swap(u3,u1): u1 -> W1(keys 2,3), u3 -> W3(keys 6,7)
#define PACK_SLICE(SC, B, DST)                                                   \
  {                                                                              \
    uint32_t u0, u1, u2, u3;                                                     \
    asm("v_cvt_pk_bf16_f32 %0, %1, %2" : "=v"(u0) : "v"(SC[B+0]), "v"(SC[B+1])); \
    asm("v_cvt_pk_bf16_f32 %0, %1, %2" : "=v"(u1) : "v"(SC[B+2]), "v"(SC[B+3])); \
    asm("v_cvt_pk_bf16_f32 %0, %1, %2" : "=v"(u2) : "v"(SC[B+4]), "v"(SC[B+5])); \
    asm("v_cvt_pk_bf16_f32 %0, %1, %2" : "=v"(u3) : "v"(SC[B+6]), "v"(SC[B+7])); \
    asm("v_permlane32_swap_b32 %0, %1" : "+v"(u2), "+v"(u0));                    \
    asm("v_permlane32_swap_b32 %0, %1" : "+v"(u3), "+v"(u1));                    \
    union { uint32_t w[4]; bf16x8 v; } pu_;                                      \
    pu_.w[0] = u0; pu_.w[1] = u1; pu_.w[2] = u2; pu_.w[3] = u3;                  \
    DST = pu_.v;                                                                 \
  }

__global__ __launch_bounds__(256)
void flash_attn(const u16* __restrict__ qkv, const u16* __restrict__ Vt,
                u16* __restrict__ Ob) {
  __shared__ __align__(16) u16 lK[2][64 * LKW];    // 2 x 16384 B
  __shared__ __align__(16) u16 lV[2][96 * LVW];    // 2 x 12288 B (total 57344)
  const int tid = threadIdx.x, wave = tid >> 6, lane = tid & 63;
  const int l32 = lane & 31, half = lane >> 5, l7 = lane & 7;
  // XCD-aware decode: lin%8 = XCD; 4 heads/XCD; 16 q-blocks per head.
  const int lin = blockIdx.x;
  const int bh = (lin & 7) * 4 + ((lin >> 3) & 3);
  const int qb = lin >> 5;
  const int b = bh >> 3, h = bh & 7;
  const int q0 = qb * 128 + wave * 32;
  const u16* Qp = qkv;
  const u16* KpB = qkv + 768 + (size_t)b * SEQ * QKVN + h * DK;
  const u16* VtB = Vt + (size_t)bh * DK * SEQ;
  const float cs = 0.10206207262f * LOG2E;  // (1/sqrt(96)) * log2(e)
  const float Ms = 16.0f * cs;              // fixed shift (folded)

  // Q^T B-fragments: lane holds q = l32, dk = d*16 + half*8 + [0..7]
  bf16x8 qf[6];
#pragma unroll
  for (int d = 0; d < 6; d++)
    qf[d] = ld8(Qp + (size_t)(b * SEQ + q0 + l32) * QKVN + h * DK + d * 16 + half * 8);

  f32x16 of[3] = {};     // O^T accumulators: D[dk 32-block][q=l32]
  float l_lane = 0.f;    // per-lane softmax denom partial (this lane's keys)

  // DMA one K/V tile: K = 1024 chunks (4/thread), V = 768 (3/thread).
  auto stage = [&](int kt, int buf) {
#pragma unroll
    for (int i = 0; i < 4; i++) {
      int s = i * 256 + tid;
      int row = s >> 4;
      int c = (s & 15) ^ (row & 7);
      if (c > 11) c = 11;                    // pad slot: duplicate, never read
      async16(KpB + (size_t)(kt + row) * QKVN + c * 8,
              &lK[buf][(i * 256 + wave * 64) * 8]);
    }
#pragma unroll
    for (int i = 0; i < 3; i++) {
      int s = i * 256 + tid;
      int row = s >> 3;
      int c = (s & 7) ^ (row & 7);           // always < 8, no pad
      async16(VtB + (size_t)row * SEQ + kt + c * 8,
              &lV[buf][(i * 256 + wave * 64) * 8]);
    }
  };

  stage(0, 0);
  int cur = 0;

  for (int kt = 0; kt < SEQ; kt += 64) {
    __syncthreads();  // drains DMA for buf[cur]; protects buf[cur^1] reuse
    if (kt + 64 < SEQ) stage(kt + 64, cur ^ 1);

    // S^T = K Q^T : sc0 = keys kt+[0,32), sc1 = keys kt+[32,64); col = q
    f32x16 sc0 = {}, sc1 = {};
    __builtin_amdgcn_s_setprio(1);
#pragma unroll
    for (int d = 0; d < 6; d++) {
      const int sl = ((d * 2 + half) ^ l7) << 3;
      bf16x8 k0 = ld8(&lK[cur][l32 * LKW + sl]);
      bf16x8 k1 = ld8(&lK[cur][(32 + l32) * LKW + sl]);
      sc0 = __builtin_amdgcn_mfma_f32_32x32x16_bf16(k0, qf[d], sc0, 0, 0, 0);
      sc1 = __builtin_amdgcn_mfma_f32_32x32x16_bf16(k1, qf[d], sc1, 0, 0, 0);
    }
    __builtin_amdgcn_s_setprio(0);

    // P = exp2(s*cs - Ms), in place; accumulate per-lane l
#pragma unroll
    for (int r = 0; r < 16; r++) {
      float p0 = __builtin_amdgcn_exp2f(sc0[r] * cs - Ms);
      float p1 = __builtin_amdgcn_exp2f(sc1[r] * cs - Ms);
      l_lane += p0 + p1;
      sc0[r] = p0;
      sc1[r] = p1;
    }

    // pack P^T into 4 B-fragments (16 keys each) via cvt_pk + permlane32_swap
    bf16x8 pa[4];
    PACK_SLICE(sc0, 0, pa[0])
    PACK_SLICE(sc0, 8, pa[1])
    PACK_SLICE(sc1, 0, pa[2])
    PACK_SLICE(sc1, 8, pa[3])

    // O^T += V^T P^T
    __builtin_amdgcn_s_setprio(1);
#pragma unroll
    for (int ks = 0; ks < 4; ks++) {
      const int sl = ((ks * 2 + half) ^ l7) << 3;
#pragma unroll
      for (int db = 0; db < 3; db++) {
        bf16x8 va = ld8(&lV[cur][(db * 32 + l32) * LVW + sl]);
        of[db] = __builtin_amdgcn_mfma_f32_32x32x16_bf16(va, pa[ks], of[db], 0, 0, 0);
      }
    }
    __builtin_amdgcn_s_setprio(0);
    cur ^= 1;
  }

  // epilogue: combine the two half-lane l partials (same q), divide, store
  float lt = l_lane + __shfl_xor(l_lane, 32);
  float inv = 1.f / lt;
  const int q = q0 + l32;
  u16* Orow = Ob + (size_t)(b * SEQ + q) * DM + h * DK;
#pragma unroll
  for (int db = 0; db < 3; db++)
#pragma unroll
    for (int r = 0; r < 16; r++) {
      int dk = db * 32 + (r & 3) + 8 * (r >> 2) + 4 * half;
      Orow[dk] = f2bf(of[db][r] * inv);
    }
}

// ---------- LayerNorm: out = LN(y); outf and/or outb optional ----------
__global__ __launch_bounds__(256)
void ln_kernel(const float* __restrict__ y, const float* __restrict__ g,
               const float* __restrict__ be, float* __restrict__ outf,
               u16* __restrict__ outb) {
  int row = blockIdx.x, t = threadIdx.x;
  const float* yr = y + (size_t)row * DM;
  float v[3], s = 0.f, s2 = 0.f;
#pragma unroll
  for (int i = 0; i < 3; i++) {
    v[i] = yr[t + i * 256];
    s += v[i];
    s2 += v[i] * v[i];
  }
#pragma unroll
  for (int m = 1; m < 64; m <<= 1) {
    s += __shfl_xor(s, m);
    s2 += __shfl_xor(s2, m);
  }
  __shared__ float red[2][4];
  int w = t >> 6;
  if ((t & 63) == 0) { red[0][w] = s; red[1][w] = s2; }
  __syncthreads();
  s = red[0][0] + red[0][1] + red[0][2] + red[0][3];
  s2 = red[1][0] + red[1][1] + red[1][2] + red[1][3];
  float mu = s * (1.f / DM);
  float var = s2 * (1.f / DM) - mu * mu;
  float rs = rsqrtf(var + 1e-5f);
#pragma unroll
  for (int i = 0; i < 3; i++) {
    int e = t + i * 256;
    float o = (v[i] - mu) * rs * g[e] + be[e];
    if (outf) outf[(size_t)row * DM + e] = o;
    if (outb) outb[(size_t)row * DM + e] = f2bf(o);
  }
}

// ---------- workspace layout (bytes) ----------
#define SZ_BF 12582912ull            // 8192*768*2
#define SZ_F  25165824ull            // 8192*768*4
#define O_XB   0ull                                  // x bf16; later attn_out
#define O_WT   (O_XB + SZ_BF)                        // qkv^T concat [2304][768] bf16
#define O_WOT  (O_WT + 3538944ull)
#define O_W1T  (O_WOT + 1179648ull)
#define O_W2T  (O_W1T + 3145728ull)
#define O_QKV  (O_W2T + 3145728ull)                  // [8192][2304] bf16; later x1b + h
#define O_VT   (O_QKV + 37748736ull)                 // [32][96][2048] bf16
#define O_Y    (O_VT + SZ_BF)                        // fp32 pre-LN buffer
#define O_X1F  (O_Y + SZ_F)                          // (unused now)
#define O_BIAS (O_X1F + SZ_F)                        // 2304 fp32 concat qkv bias

extern "C" void kernel_launch(void* const* d_in, const int* in_sizes, int n_in,
                              void* d_out, int out_size, void* d_ws, size_t ws_size,
                              hipStream_t stream) {
  const float* x   = (const float*)d_in[0];
  const float* Wq  = (const float*)d_in[1];
  const float* bq  = (const float*)d_in[2];
  const float* Wk  = (const float*)d_in[3];
  const float* bk  = (const float*)d_in[4];
  const float* Wv  = (const float*)d_in[5];
  const float* bv  = (const float*)d_in[6];
  const float* Wo  = (const float*)d_in[7];
  const float* bo  = (const float*)d_in[8];
  const float* g1  = (const float*)d_in[9];
  const float* be1 = (const float*)d_in[10];
  const float* W1  = (const float*)d_in[11];
  const float* b1  = (const float*)d_in[12];
  const float* W2  = (const float*)d_in[13];
  const float* b2  = (const float*)d_in[14];
  const float* g2  = (const float*)d_in[15];
  const float* be2 = (const float*)d_in[16];
  float* out = (float*)d_out;
  char* ws = (char*)d_ws;

  u16* xb    = (u16*)(ws + O_XB);
  u16* WT    = (u16*)(ws + O_WT);
  u16* WoT   = (u16*)(ws + O_WOT);
  u16* W1T   = (u16*)(ws + O_W1T);
  u16* W2T   = (u16*)(ws + O_W2T);
  u16* qkv   = (u16*)(ws + O_QKV);
  u16* vt    = (u16*)(ws + O_VT);
  float* y   = (float*)(ws + O_Y);
  float* bqkv = (float*)(ws + O_BIAS);
  u16* ao   = xb;                       // alias: xb dead after QKV GEMM
  u16* x1b  = qkv;                      // alias: qkv dead after attention
  u16* hbuf = qkv + (size_t)MTOK * DM;  // h [8192][2048] bf16

  // fused prep (one dispatch)
  prep<<<11529, 256, 0, stream>>>(x, xb, bq, bk, bv, bqkv,
                                  Wq, Wk, Wv, Wo, W1, W2,
                                  WT, WoT, W1T, W2T);

  // QKV projection (fused N=2304)
  gemm_bt<0, 0, 1><<<dim3(18, 64), 256, 0, stream>>>(xb, WT, bqkv, nullptr, nullptr, qkv, QKVN, DM);
  // V^T for PV A-operand
  transpose_v<<<dim3(64, 3, 32), dim3(32, 8), 0, stream>>>(qkv + 1536, vt);
  // attention: 512 blocks x 256 threads (4 waves x 32 q-rows, 2 blocks/CU)
  flash_attn<<<512, 256, 0, stream>>>(qkv, vt, ao);
  // out projection + residual(x fp32) -> y (fp32): N=768, 128x64 tiles
  gemm_bt64<1, 0, 0, 0><<<dim3(12, 64), 256, 0, stream>>>(ao, WoT, bo, x, nullptr, y, nullptr, DM, DM);
  // LN1 -> x1b (bf16 only; fp32 x1 round-trip eliminated)
  ln_kernel<<<8192, 256, 0, stream>>>(y, g1, be1, nullptr, x1b);
  // FFN1 + ReLU -> h (bf16)
  gemm_bt<0, 1, 1><<<dim3(16, 64), 256, 0, stream>>>(x1b, W1T, b1, nullptr, nullptr, hbuf, DFF, DM);
  // FFN2 + residual(x1b bf16) -> y (fp32): N=768, 128x64 tiles
  gemm_bt64<1, 0, 0, 1><<<dim3(12, 64), 256, 0, stream>>>(hbuf, W2T, b2, nullptr, x1b, y, nullptr, DM, DFF);
  // LN2 -> out
  ln_kernel<<<8192, 256, 0, stream>>>(y, g2, be2, out, nullptr);
}

// Round 4
// 342.828 us; speedup vs baseline: 1.2036x; 1.0072x over previous
//
#include <hip/hip_runtime.h>
#include <cstdint>
#include <cstddef>

typedef unsigned short u16;
typedef __bf16 bf16x8 __attribute__((ext_vector_type(8)));
typedef float f32x4 __attribute__((ext_vector_type(4)));
typedef float f32x16 __attribute__((ext_vector_type(16)));

// ---------- constants ----------
#define BATCH 4
#define SEQ   2048
#define DM    768
#define NH    8
#define DK    96
#define DFF   2048
#define MTOK  8192          // BATCH*SEQ
#define QKVN  2304          // 3*DM
#define LOG2E 1.44269504088896340736f

// ---------- helpers ----------
__device__ __forceinline__ u16 f2bf(float f) {
  union { float f; uint32_t u; } v; v.f = f;
  return (u16)((v.u + 0x7fffu + ((v.u >> 16) & 1u)) >> 16);
}
__device__ __forceinline__ float bf2f(u16 b) {
  union { uint32_t u; float f; } v; v.u = (uint32_t)b << 16;
  return v.f;
}
__device__ __forceinline__ bf16x8 ld8(const u16* p) { return *(const bf16x8*)p; }
__device__ __forceinline__ void async16(const u16* g, u16* l) {
  __builtin_amdgcn_global_load_lds((const __attribute__((address_space(1))) void*)g,
                                   (__attribute__((address_space(3))) void*)l, 16, 0, 0);
}

// ---------- fused prep: cast_bf16 + concat3 + 6 weight transposes ----------
__global__ __launch_bounds__(256)
void prep(const float* __restrict__ x, u16* __restrict__ xb,
          const float* __restrict__ bq, const float* __restrict__ bk,
          const float* __restrict__ bv, float* __restrict__ bqkv,
          const float* __restrict__ Wq, const float* __restrict__ Wk,
          const float* __restrict__ Wv, const float* __restrict__ Wo,
          const float* __restrict__ W1, const float* __restrict__ W2,
          u16* __restrict__ WT, u16* __restrict__ WoT,
          u16* __restrict__ W1T, u16* __restrict__ W2T) {
  __shared__ float t[32][33];
  const int tid = threadIdx.x;
  int bid = blockIdx.x;

  if (bid < 6144) {                       // cast x (8192x768 fp32 -> bf16)
    size_t i = (size_t)bid * 1024 + tid * 4;
    float4 f = *(const float4*)(x + i);
    uint2 o;
    o.x = (unsigned)f2bf(f.x) | ((unsigned)f2bf(f.y) << 16);
    o.y = (unsigned)f2bf(f.z) | ((unsigned)f2bf(f.w) << 16);
    *(uint2*)(xb + i) = o;
    return;
  }
  if (bid < 6153) {                       // concat qkv bias (2304)
    int i = (bid - 6144) * 256 + tid;
    float v = (i < 768) ? bq[i] : (i < 1536) ? bk[i - 768] : bv[i - 1536];
    bqkv[i] = v;
    return;
  }
  bid -= 6153;
  const float* in; u16* out; int C, R, bx, by;
  if (bid < 576)       { in = Wq; out = WT;                 C = 768;  R = 768;  bx = bid % 24;          by = bid / 24; }
  else if (bid < 1152) { in = Wk; out = WT + 768 * 768;     C = 768;  R = 768;  bx = (bid - 576) % 24;  by = (bid - 576) / 24; }
  else if (bid < 1728) { in = Wv; out = WT + 2 * 768 * 768; C = 768;  R = 768;  bx = (bid - 1152) % 24; by = (bid - 1152) / 24; }
  else if (bid < 2304) { in = Wo; out = WoT;                C = 768;  R = 768;  bx = (bid - 1728) % 24; by = (bid - 1728) / 24; }
  else if (bid < 3840) { in = W1; out = W1T;                C = 2048; R = 768;  bx = (bid - 2304) % 64; by = (bid - 2304) / 64; }
  else                 { in = W2; out = W2T;                C = 768;  R = 2048; bx = (bid - 3840) % 24; by = (bid - 3840) / 24; }
  const int r0 = by * 32, c0 = bx * 32;
  const int tx = tid & 31, ty = tid >> 5;
#pragma unroll
  for (int i = 0; i < 4; i++)
    t[ty + i * 8][tx] = in[(size_t)(r0 + ty + i * 8) * C + c0 + tx];
  __syncthreads();
#pragma unroll
  for (int i = 0; i < 4; i++)
    out[(size_t)(c0 + ty + i * 8) * R + r0 + tx] = f2bf(t[tx][ty + i * 8]);
}

// v part of qkv (stride 2304) -> vt [B*H][96][2048] bf16
__global__ void transpose_v(const u16* __restrict__ v, u16* __restrict__ vt) {
  __shared__ u16 t[32][33];
  int bh = blockIdx.z, b = bh >> 3, h = bh & 7;
  int s0 = blockIdx.x * 32, d0 = blockIdx.y * 32;
  int tx = threadIdx.x, ty = threadIdx.y;
#pragma unroll
  for (int i = 0; i < 4; i++)
    t[ty + i * 8][tx] = v[(size_t)(b * SEQ + s0 + ty + i * 8) * QKVN + h * DK + d0 + tx];
  __syncthreads();
#pragma unroll
  for (int i = 0; i < 4; i++)
    vt[(size_t)(bh * DK + d0 + ty + i * 8) * SEQ + s0 + tx] = t[tx][ty + i * 8];
}

// ---------- GEMM: C[M,N] = A[M,K] @ BT[N,K]^T + bias (+resid)(+relu) ----------
template <int RESID, int RELU, int OUTBF>
__global__ __launch_bounds__(256, 4)
void gemm_bt(const u16* __restrict__ A, const u16* __restrict__ BT,
             const float* __restrict__ bias, const float* __restrict__ resid,
             float* __restrict__ Cf, u16* __restrict__ Cb, int N, int K) {
  __shared__ __align__(16) u16 lA[128 * 64];
  __shared__ __align__(16) u16 lB[128 * 64];
  const int tid = threadIdx.x;
  const int wave = tid >> 6, lane = tid & 63;
  const int quad = lane >> 4, l16 = lane & 15;
  const int wm = wave >> 1, wn = wave & 1;
  const int tm = blockIdx.y * 128, tn = blockIdx.x * 128;

  f32x4 acc[4][4] = {};

  for (int k0 = 0; k0 < K; k0 += 64) {
    __syncthreads();
#pragma unroll
    for (int i = 0; i < 4; i++) {
      int cbase = (wave * 4 + i) * 64;
      int c = cbase + lane;
      int row = c >> 3;
      int scc = (c & 7) ^ (row & 7);           // XOR swizzle of 16B chunks
      async16(A + (size_t)(tm + row) * K + k0 + scc * 8, &lA[cbase * 8]);
      async16(BT + (size_t)(tn + row) * K + k0 + scc * 8, &lB[cbase * 8]);
    }
    __syncthreads();
#pragma unroll
    for (int ks = 0; ks < 2; ks++) {
      bf16x8 af[4], bfr[4];
#pragma unroll
      for (int i = 0; i < 4; i++) {
        int ra = wm * 64 + i * 16 + l16;
        af[i] = ld8(&lA[ra * 64 + (((ks * 4 + quad) ^ (ra & 7)) << 3)]);
        int rb = wn * 64 + i * 16 + l16;
        bfr[i] = ld8(&lB[rb * 64 + (((ks * 4 + quad) ^ (rb & 7)) << 3)]);
      }
#pragma unroll
      for (int i = 0; i < 4; i++)
#pragma unroll
        for (int j = 0; j < 4; j++)
          acc[i][j] = __builtin_amdgcn_mfma_f32_16x16x32_bf16(af[i], bfr[j], acc[i][j], 0, 0, 0);
    }
  }

#pragma unroll
  for (int i = 0; i < 4; i++) {
    const int row0 = tm + wm * 64 + i * 16 + quad * 4;
#pragma unroll
    for (int j = 0; j < 4; j++) {
      const int col = tn + wn * 64 + j * 16 + l16;
      const float bv = bias[col];
#pragma unroll
      for (int r = 0; r < 4; r++) {
        float v = acc[i][j][r] + bv;
        if (RESID) v += resid[(size_t)(row0 + r) * N + col];
        if (RELU) v = fmaxf(v, 0.f);
        if (OUTBF) Cb[(size_t)(row0 + r) * N + col] = f2bf(v);
        else       Cf[(size_t)(row0 + r) * N + col] = v;
      }
    }
  }
}

// ---------- GEMM 128x64 tile (N=768: 768 blocks) ----------
template <int RESID, int RELU, int OUTBF, int RESBF>
__global__ __launch_bounds__(256, 4)
void gemm_bt64(const u16* __restrict__ A, const u16* __restrict__ BT,
               const float* __restrict__ bias, const float* __restrict__ residf,
               const u16* __restrict__ residb,
               float* __restrict__ Cf, u16* __restrict__ Cb, int N, int K) {
  __shared__ __align__(16) u16 lA[128 * 64];
  __shared__ __align__(16) u16 lB[64 * 64];
  const int tid = threadIdx.x;
  const int wave = tid >> 6, lane = tid & 63;
  const int quad = lane >> 4, l16 = lane & 15;
  const int wm = wave >> 1, wn = wave & 1;
  const int tm = blockIdx.y * 128, tn = blockIdx.x * 64;

  f32x4 acc[4][2] = {};

  for (int k0 = 0; k0 < K; k0 += 64) {
    __syncthreads();
#pragma unroll
    for (int i = 0; i < 4; i++) {
      int cbase = (wave * 4 + i) * 64;
      int c = cbase + lane;
      int row = c >> 3;
      int scc = (c & 7) ^ (row & 7);
      async16(A + (size_t)(tm + row) * K + k0 + scc * 8, &lA[cbase * 8]);
    }
#pragma unroll
    for (int i = 0; i < 2; i++) {
      int cbase = (wave * 2 + i) * 64;
      int c = cbase + lane;
      int row = c >> 3;
      int scc = (c & 7) ^ (row & 7);
      async16(BT + (size_t)(tn + row) * K + k0 + scc * 8, &lB[cbase * 8]);
    }
    __syncthreads();
#pragma unroll
    for (int ks = 0; ks < 2; ks++) {
      bf16x8 af[4], bfr[2];
#pragma unroll
      for (int i = 0; i < 4; i++) {
        int ra = wm * 64 + i * 16 + l16;
        af[i] = ld8(&lA[ra * 64 + (((ks * 4 + quad) ^ (ra & 7)) << 3)]);
      }
#pragma unroll
      for (int j = 0; j < 2; j++) {
        int rb = wn * 32 + j * 16 + l16;
        bfr[j] = ld8(&lB[rb * 64 + (((ks * 4 + quad) ^ (rb & 7)) << 3)]);
      }
#pragma unroll
      for (int i = 0; i < 4; i++)
#pragma unroll
        for (int j = 0; j < 2; j++)
          acc[i][j] = __builtin_amdgcn_mfma_f32_16x16x32_bf16(af[i], bfr[j], acc[i][j], 0, 0, 0);
    }
  }

#pragma unroll
  for (int i = 0; i < 4; i++) {
    const int row0 = tm + wm * 64 + i * 16 + quad * 4;
#pragma unroll
    for (int j = 0; j < 2; j++) {
      const int col = tn + wn * 32 + j * 16 + l16;
      const float bv = bias[col];
#pragma unroll
      for (int r = 0; r < 4; r++) {
        float v = acc[i][j][r] + bv;
        if (RESID) {
          if (RESBF) v += bf2f(residb[(size_t)(row0 + r) * N + col]);
          else       v += residf[(size_t)(row0 + r) * N + col];
        }
        if (RELU) v = fmaxf(v, 0.f);
        if (OUTBF) Cb[(size_t)(row0 + r) * N + col] = f2bf(v);
        else       Cf[(size_t)(row0 + r) * N + col] = v;
      }
    }
  }
}

// ---------- flash attention v11: wave-pair split, 16 waves/CU ----------
// Round-3 post-mortem: latency-bound at 2 waves/SIMD (no pipe >50%). Fix:
// 512-thread blocks, 8 waves; wave w owns (q-sub = w>>1, key-half = w&1):
// 32 q x 32 keys. Per-wave state halves (sc 16 regs, VGPR ~85 << 128 cap,
// no R1-style spill); grid stays 512 = 2 blocks/CU -> 4 waves/SIMD.
// lK pad chunks dropped (16 -> 12 slots/row, div-12 staging): LDS 57,344 ->
// 49,152 B and K DMA -25%. Wave pairs sum partial O/l via LDS in epilogue.
#define KROW 96   // lK row stride u16 (12 chunks, swizzled, no pad)
#define VROW 64   // lV row stride u16 (8 chunks, swizzled)

// pack one 16-key slice (8 f32 score regs) into one PV B-fragment.
#define PACK_SLICE(SC, B, DST)                                                   \
  {                                                                              \
    uint32_t u0, u1, u2, u3;                                                     \
    asm("v_cvt_pk_bf16_f32 %0, %1, %2" : "=v"(u0) : "v"(SC[B+0]), "v"(SC[B+1])); \
    asm("v_cvt_pk_bf16_f32 %0, %1, %2" : "=v"(u1) : "v"(SC[B+2]), "v"(SC[B+3])); \
    asm("v_cvt_pk_bf16_f32 %0, %1, %2" : "=v"(u2) : "v"(SC[B+4]), "v"(SC[B+5])); \
    asm("v_cvt_pk_bf16_f32 %0, %1, %2" : "=v"(u3) : "v"(SC[B+6]), "v"(SC[B+7])); \
    asm("v_permlane32_swap_b32 %0, %1" : "+v"(u2), "+v"(u0));                    \
    asm("v_permlane32_swap_b32 %0, %1" : "+v"(u3), "+v"(u1));                    \
    union { uint32_t w[4]; bf16x8 v; } pu_;                                      \
    pu_.w[0] = u0; pu_.w[1] = u1; pu_.w[2] = u2; pu_.w[3] = u3;                  \
    DST = pu_.v;                                                                 \
  }

__global__ __launch_bounds__(512, 4)
void flash_attn(const u16* __restrict__ qkv, const u16* __restrict__ Vt,
                u16* __restrict__ Ob) {
  // one flat buffer: lK = [2][64*96] u16 (24,576 B), lV = [2][96*64] u16
  // (24,576 B); total 49,152 B. Epilogue aliases it as float exchange area.
  __shared__ __align__(16) u16 smem[24576];
  u16* lKp = smem;           // + buf*6144
  u16* lVp = smem + 12288;   // + buf*6144
  const int tid = threadIdx.x, wave = tid >> 6, lane = tid & 63;
  const int l32 = lane & 31, half = lane >> 5;
  const int qsub = wave >> 1, kodd = wave & 1, pair = wave >> 1;
  // XCD-aware decode: lin%8 = XCD; 4 heads/XCD; 16 q-blocks per head.
  const int lin = blockIdx.x;
  const int bh = (lin & 7) * 4 + ((lin >> 3) & 3);
  const int qb = lin >> 5;
  const int b = bh >> 3, h = bh & 7;
  const int q0 = qb * 128 + qsub * 32;
  const u16* Qp = qkv;
  const u16* KpB = qkv + 768 + (size_t)b * SEQ * QKVN + h * DK;
  const u16* VtB = Vt + (size_t)bh * DK * SEQ;
  const float cs = 0.10206207262f * LOG2E;  // (1/sqrt(96)) * log2(e)
  const float Ms = 16.0f * cs;              // fixed shift (folded)

  // Q^T B-fragments: lane holds q = l32, dk = d*16 + half*8 + [0..7]
  bf16x8 qf[6];
#pragma unroll
  for (int d = 0; d < 6; d++)
    qf[d] = ld8(Qp + (size_t)(b * SEQ + q0 + l32) * QKVN + h * DK + d * 16 + half * 8);

  f32x16 of[3] = {};     // O^T partial (this wave's 32-key half): D[dk blk][q=l32]
  float l_lane = 0.f;    // per-lane softmax denom partial

  // DMA one K/V tile with 512 threads: K = 768 chunks [64 rows][12 slots]
  // (slot s holds global chunk g: s<8 -> (s^row)&7, else 8+((s^row)&3));
  // V = 768 chunks [96 rows][8 slots] (slot s -> chunk (s^row)&7).
  auto stage = [&](int kt, int buf) {
    {
      int sl = tid;                        // 0..511
      int row = sl / 12, s = sl % 12;
      int g = (s < 8) ? ((s ^ row) & 7) : (8 + ((s ^ row) & 3));
      async16(KpB + (size_t)(kt + row) * QKVN + g * 8, &lKp[buf * 6144 + sl * 8]);
    }
    if (tid < 256) {
      int sl = 512 + tid;                  // 512..767
      int row = sl / 12, s = sl % 12;
      int g = (s < 8) ? ((s ^ row) & 7) : (8 + ((s ^ row) & 3));
      async16(KpB + (size_t)(kt + row) * QKVN + g * 8, &lKp[buf * 6144 + sl * 8]);
    }
    {
      int s = tid;
      int row = s >> 3, c = (s ^ row) & 7;
      async16(VtB + (size_t)row * SEQ + kt + c * 8, &lVp[buf * 6144 + s * 8]);
    }
    if (tid < 256) {
      int s = 512 + tid;
      int row = s >> 3, c = (s ^ row) & 7;
      async16(VtB + (size_t)row * SEQ + kt + c * 8, &lVp[buf * 6144 + s * 8]);
    }
  };

  stage(0, 0);
  int cur = 0;

  for (int kt = 0; kt < SEQ; kt += 64) {
    __syncthreads();  // drains DMA for buf[cur]; protects buf[cur^1] reuse
    if (kt + 64 < SEQ) stage(kt + 64, cur ^ 1);

    // S^T = K Q^T for this wave's 32-key half; col = q
    f32x16 sc = {};
    const int krow = kodd * 32 + l32;
    __builtin_amdgcn_s_setprio(1);
#pragma unroll
    for (int d = 0; d < 6; d++) {
      int g = d * 2 + half;
      int slot = (d < 4) ? ((g ^ krow) & 7) : (8 + ((g ^ krow) & 3));
      bf16x8 kb = ld8(&lKp[cur * 6144 + krow * KROW + slot * 8]);
      sc = __builtin_amdgcn_mfma_f32_32x32x16_bf16(kb, qf[d], sc, 0, 0, 0);
    }
    __builtin_amdgcn_s_setprio(0);

    // P = exp2(s*cs - Ms), in place; accumulate per-lane l
#pragma unroll
    for (int r = 0; r < 16; r++) {
      float p = __builtin_amdgcn_exp2f(sc[r] * cs - Ms);
      l_lane += p;
      sc[r] = p;
    }

    // pack P^T into 2 B-fragments (16 keys each)
    bf16x8 pa[2];
    PACK_SLICE(sc, 0, pa[0])
    PACK_SLICE(sc, 8, pa[1])

    // O^T += V^T P^T  (this wave's 32 keys)
    __builtin_amdgcn_s_setprio(1);
#pragma unroll
    for (int ks = 0; ks < 2; ks++) {
      int gv = kodd * 4 + ks * 2 + half;
#pragma unroll
      for (int db = 0; db < 3; db++) {
        int vrow = db * 32 + l32;
        int slot = (gv ^ vrow) & 7;
        bf16x8 va = ld8(&lVp[cur * 6144 + vrow * VROW + slot * 8]);
        of[db] = __builtin_amdgcn_mfma_f32_32x32x16_bf16(va, pa[ks], of[db], 0, 0, 0);
      }
    }
    __builtin_amdgcn_s_setprio(0);
    cur ^= 1;
  }

  // ---- epilogue: wave-pair combine via LDS, divide, store ----
  float lw = l_lane + __shfl_xor(l_lane, 32);   // this wave's l per q=l32
  float linv = 0.f;
  float* xf = (float*)smem;
  const int q = q0 + l32;
  u16* Orow = Ob + (size_t)(b * SEQ + q) * DM + h * DK;

  __syncthreads();                               // S1: loop done, smem free
  if (kodd) {                                    // phase A write: of[0,1] + lw
    float* dst = xf + (pair * 64 + lane) * 33;
#pragma unroll
    for (int r = 0; r < 16; r++) { dst[r] = of[0][r]; dst[16 + r] = of[1][r]; }
    dst[32] = lw;
  }
  __syncthreads();                               // S2
  if (!kodd) {
    const float* src = xf + (pair * 64 + lane) * 33;
    linv = 1.f / (lw + src[32]);
#pragma unroll
    for (int db = 0; db < 2; db++)
#pragma unroll
      for (int r = 0; r < 16; r++) {
        int dk = db * 32 + (r & 3) + 8 * (r >> 2) + 4 * half;
        Orow[dk] = f2bf((of[db][r] + src[db * 16 + r]) * linv);
      }
  }
  __syncthreads();                               // S3: phase A reads done
  if (kodd) {                                    // phase B write: of[2]
    float* dst = xf + (pair * 64 + lane) * 16;
#pragma unroll
    for (int r = 0; r < 16; r++) dst[r] = of[2][r];
  }
  __syncthreads();                               // S4
  if (!kodd) {
    const float* src = xf + (pair * 64 + lane) * 16;
#pragma unroll
    for (int r = 0; r < 16; r++) {
      int dk = 64 + (r & 3) + 8 * (r >> 2) + 4 * half;
      Orow[dk] = f2bf((of[2][r] + src[r]) * linv);
    }
  }
}

// ---------- LayerNorm: out = LN(y); outf and/or outb optional ----------
__global__ __launch_bounds__(256)
void ln_kernel(const float* __restrict__ y, const float* __restrict__ g,
               const float* __restrict__ be, float* __restrict__ outf,
               u16* __restrict__ outb) {
  int row = blockIdx.x, t = threadIdx.x;
  const float* yr = y + (size_t)row * DM;
  float v[3], s = 0.f, s2 = 0.f;
#pragma unroll
  for (int i = 0; i < 3; i++) {
    v[i] = yr[t + i * 256];
    s += v[i];
    s2 += v[i] * v[i];
  }
#pragma unroll
  for (int m = 1; m < 64; m <<= 1) {
    s += __shfl_xor(s, m);
    s2 += __shfl_xor(s2, m);
  }
  __shared__ float red[2][4];
  int w = t >> 6;
  if ((t & 63) == 0) { red[0][w] = s; red[1][w] = s2; }
  __syncthreads();
  s = red[0][0] + red[0][1] + red[0][2] + red[0][3];
  s2 = red[1][0] + red[1][1] + red[1][2] + red[1][3];
  float mu = s * (1.f / DM);
  float var = s2 * (1.f / DM) - mu * mu;
  float rs = rsqrtf(var + 1e-5f);
#pragma unroll
  for (int i = 0; i < 3; i++) {
    int e = t + i * 256;
    float o = (v[i] - mu) * rs * g[e] + be[e];
    if (outf) outf[(size_t)row * DM + e] = o;
    if (outb) outb[(size_t)row * DM + e] = f2bf(o);
  }
}

// ---------- workspace layout (bytes) ----------
#define SZ_BF 12582912ull            // 8192*768*2
#define SZ_F  25165824ull            // 8192*768*4
#define O_XB   0ull                                  // x bf16; later attn_out
#define O_WT   (O_XB + SZ_BF)                        // qkv^T concat [2304][768] bf16
#define O_WOT  (O_WT + 3538944ull)
#define O_W1T  (O_WOT + 1179648ull)
#define O_W2T  (O_W1T + 3145728ull)
#define O_QKV  (O_W2T + 3145728ull)                  // [8192][2304] bf16; later x1b + h
#define O_VT   (O_QKV + 37748736ull)                 // [32][96][2048] bf16
#define O_Y    (O_VT + SZ_BF)                        // fp32 pre-LN buffer
#define O_X1F  (O_Y + SZ_F)                          // (unused now)
#define O_BIAS (O_X1F + SZ_F)                        // 2304 fp32 concat qkv bias

extern "C" void kernel_launch(void* const* d_in, const int* in_sizes, int n_in,
                              void* d_out, int out_size, void* d_ws, size_t ws_size,
                              hipStream_t stream) {
  const float* x   = (const float*)d_in[0];
  const float* Wq  = (const float*)d_in[1];
  const float* bq  = (const float*)d_in[2];
  const float* Wk  = (const float*)d_in[3];
  const float* bk  = (const float*)d_in[4];
  const float* Wv  = (const float*)d_in[5];
  const float* bv  = (const float*)d_in[6];
  const float* Wo  = (const float*)d_in[7];
  const float* bo  = (const float*)d_in[8];
  const float* g1  = (const float*)d_in[9];
  const float* be1 = (const float*)d_in[10];
  const float* W1  = (const float*)d_in[11];
  const float* b1  = (const float*)d_in[12];
  const float* W2  = (const float*)d_in[13];
  const float* b2  = (const float*)d_in[14];
  const float* g2  = (const float*)d_in[15];
  const float* be2 = (const float*)d_in[16];
  float* out = (float*)d_out;
  char* ws = (char*)d_ws;

  u16* xb    = (u16*)(ws + O_XB);
  u16* WT    = (u16*)(ws + O_WT);
  u16* WoT   = (u16*)(ws + O_WOT);
  u16* W1T   = (u16*)(ws + O_W1T);
  u16* W2T   = (u16*)(ws + O_W2T);
  u16* qkv   = (u16*)(ws + O_QKV);
  u16* vt    = (u16*)(ws + O_VT);
  float* y   = (float*)(ws + O_Y);
  float* bqkv = (float*)(ws + O_BIAS);
  u16* ao   = xb;                       // alias: xb dead after QKV GEMM
  u16* x1b  = qkv;                      // alias: qkv dead after attention
  u16* hbuf = qkv + (size_t)MTOK * DM;  // h [8192][2048] bf16

  // fused prep (one dispatch)
  prep<<<11529, 256, 0, stream>>>(x, xb, bq, bk, bv, bqkv,
                                  Wq, Wk, Wv, Wo, W1, W2,
                                  WT, WoT, W1T, W2T);

  // QKV projection (fused N=2304)
  gemm_bt<0, 0, 1><<<dim3(18, 64), 256, 0, stream>>>(xb, WT, bqkv, nullptr, nullptr, qkv, QKVN, DM);
  // V^T for PV A-operand
  transpose_v<<<dim3(64, 3, 32), dim3(32, 8), 0, stream>>>(qkv + 1536, vt);
  // attention: 512 blocks x 512 threads (8 waves: 4 q-subs x 2 key-halves)
  flash_attn<<<512, 512, 0, stream>>>(qkv, vt, ao);
  // out projection + residual(x fp32) -> y (fp32): N=768, 128x64 tiles
  gemm_bt64<1, 0, 0, 0><<<dim3(12, 64), 256, 0, stream>>>(ao, WoT, bo, x, nullptr, y, nullptr, DM, DM);
  // LN1 -> x1b (bf16 only; fp32 x1 round-trip eliminated)
  ln_kernel<<<8192, 256, 0, stream>>>(y, g1, be1, nullptr, x1b);
  // FFN1 + ReLU -> h (bf16)
  gemm_bt<0, 1, 1><<<dim3(16, 64), 256, 0, stream>>>(x1b, W1T, b1, nullptr, nullptr, hbuf, DFF, DM);
  // FFN2 + residual(x1b bf16) -> y (fp32): N=768, 128x64 tiles
  gemm_bt64<1, 0, 0, 1><<<dim3(12, 64), 256, 0, stream>>>(hbuf, W2T, b2, nullptr, x1b, y, nullptr, DM, DFF);
  // LN2 -> out
  ln_kernel<<<8192, 256, 0, stream>>>(y, g2, be2, out, nullptr);
}

// Round 5
// 340.701 us; speedup vs baseline: 1.2111x; 1.0062x over previous
//
#include <hip/hip_runtime.h>
#include <cstdint>
#include <cstddef>

typedef unsigned short u16;
typedef __bf16 bf16x8 __attribute__((ext_vector_type(8)));
typedef float f32x4 __attribute__((ext_vector_type(4)));
typedef float f32x16 __attribute__((ext_vector_type(16)));

// ---------- constants ----------
#define BATCH 4
#define SEQ   2048
#define DM    768
#define NH    8
#define DK    96
#define DFF   2048
#define MTOK  8192          // BATCH*SEQ
#define QKVN  2304          // 3*DM
#define LOG2E 1.44269504088896340736f

// ---------- helpers ----------
__device__ __forceinline__ u16 f2bf(float f) {
  union { float f; uint32_t u; } v; v.f = f;
  return (u16)((v.u + 0x7fffu + ((v.u >> 16) & 1u)) >> 16);
}
__device__ __forceinline__ float bf2f(u16 b) {
  union { uint32_t u; float f; } v; v.u = (uint32_t)b << 16;
  return v.f;
}
__device__ __forceinline__ bf16x8 ld8(const u16* p) { return *(const bf16x8*)p; }
__device__ __forceinline__ void async16(const u16* g, u16* l) {
  __builtin_amdgcn_global_load_lds((const __attribute__((address_space(1))) void*)g,
                                   (__attribute__((address_space(3))) void*)l, 16, 0, 0);
}

// ---------- fused prep: cast_bf16 + concat3 + 6 weight transposes ----------
__global__ __launch_bounds__(256)
void prep(const float* __restrict__ x, u16* __restrict__ xb,
          const float* __restrict__ bq, const float* __restrict__ bk,
          const float* __restrict__ bv, float* __restrict__ bqkv,
          const float* __restrict__ Wq, const float* __restrict__ Wk,
          const float* __restrict__ Wv, const float* __restrict__ Wo,
          const float* __restrict__ W1, const float* __restrict__ W2,
          u16* __restrict__ WT, u16* __restrict__ WoT,
          u16* __restrict__ W1T, u16* __restrict__ W2T) {
  __shared__ float t[32][33];
  const int tid = threadIdx.x;
  int bid = blockIdx.x;

  if (bid < 6144) {                       // cast x (8192x768 fp32 -> bf16)
    size_t i = (size_t)bid * 1024 + tid * 4;
    float4 f = *(const float4*)(x + i);
    uint2 o;
    o.x = (unsigned)f2bf(f.x) | ((unsigned)f2bf(f.y) << 16);
    o.y = (unsigned)f2bf(f.z) | ((unsigned)f2bf(f.w) << 16);
    *(uint2*)(xb + i) = o;
    return;
  }
  if (bid < 6153) {                       // concat qkv bias (2304)
    int i = (bid - 6144) * 256 + tid;
    float v = (i < 768) ? bq[i] : (i < 1536) ? bk[i - 768] : bv[i - 1536];
    bqkv[i] = v;
    return;
  }
  bid -= 6153;
  const float* in; u16* out; int C, R, bx, by;
  if (bid < 576)       { in = Wq; out = WT;                 C = 768;  R = 768;  bx = bid % 24;          by = bid / 24; }
  else if (bid < 1152) { in = Wk; out = WT + 768 * 768;     C = 768;  R = 768;  bx = (bid - 576) % 24;  by = (bid - 576) / 24; }
  else if (bid < 1728) { in = Wv; out = WT + 2 * 768 * 768; C = 768;  R = 768;  bx = (bid - 1152) % 24; by = (bid - 1152) / 24; }
  else if (bid < 2304) { in = Wo; out = WoT;                C = 768;  R = 768;  bx = (bid - 1728) % 24; by = (bid - 1728) / 24; }
  else if (bid < 3840) { in = W1; out = W1T;                C = 2048; R = 768;  bx = (bid - 2304) % 64; by = (bid - 2304) / 64; }
  else                 { in = W2; out = W2T;                C = 768;  R = 2048; bx = (bid - 3840) % 24; by = (bid - 3840) / 24; }
  const int r0 = by * 32, c0 = bx * 32;
  const int tx = tid & 31, ty = tid >> 5;
#pragma unroll
  for (int i = 0; i < 4; i++)
    t[ty + i * 8][tx] = in[(size_t)(r0 + ty + i * 8) * C + c0 + tx];
  __syncthreads();
#pragma unroll
  for (int i = 0; i < 4; i++)
    out[(size_t)(c0 + ty + i * 8) * R + r0 + tx] = f2bf(t[tx][ty + i * 8]);
}

// v part of qkv (stride 2304) -> vt [B*H][96][2048] bf16
__global__ void transpose_v(const u16* __restrict__ v, u16* __restrict__ vt) {
  __shared__ u16 t[32][33];
  int bh = blockIdx.z, b = bh >> 3, h = bh & 7;
  int s0 = blockIdx.x * 32, d0 = blockIdx.y * 32;
  int tx = threadIdx.x, ty = threadIdx.y;
#pragma unroll
  for (int i = 0; i < 4; i++)
    t[ty + i * 8][tx] = v[(size_t)(b * SEQ + s0 + ty + i * 8) * QKVN + h * DK + d0 + tx];
  __syncthreads();
#pragma unroll
  for (int i = 0; i < 4; i++)
    vt[(size_t)(bh * DK + d0 + ty + i * 8) * SEQ + s0 + tx] = t[tx][ty + i * 8];
}

// ---------- GEMM: C[M,N] = A[M,K] @ BT[N,K]^T + bias (+resid)(+relu) ----------
template <int RESID, int RELU, int OUTBF>
__global__ __launch_bounds__(256, 4)
void gemm_bt(const u16* __restrict__ A, const u16* __restrict__ BT,
             const float* __restrict__ bias, const float* __restrict__ resid,
             float* __restrict__ Cf, u16* __restrict__ Cb, int N, int K) {
  __shared__ __align__(16) u16 lA[128 * 64];
  __shared__ __align__(16) u16 lB[128 * 64];
  const int tid = threadIdx.x;
  const int wave = tid >> 6, lane = tid & 63;
  const int quad = lane >> 4, l16 = lane & 15;
  const int wm = wave >> 1, wn = wave & 1;
  const int tm = blockIdx.y * 128, tn = blockIdx.x * 128;

  f32x4 acc[4][4] = {};

  for (int k0 = 0; k0 < K; k0 += 64) {
    __syncthreads();
#pragma unroll
    for (int i = 0; i < 4; i++) {
      int cbase = (wave * 4 + i) * 64;
      int c = cbase + lane;
      int row = c >> 3;
      int scc = (c & 7) ^ (row & 7);           // XOR swizzle of 16B chunks
      async16(A + (size_t)(tm + row) * K + k0 + scc * 8, &lA[cbase * 8]);
      async16(BT + (size_t)(tn + row) * K + k0 + scc * 8, &lB[cbase * 8]);
    }
    __syncthreads();
#pragma unroll
    for (int ks = 0; ks < 2; ks++) {
      bf16x8 af[4], bfr[4];
#pragma unroll
      for (int i = 0; i < 4; i++) {
        int ra = wm * 64 + i * 16 + l16;
        af[i] = ld8(&lA[ra * 64 + (((ks * 4 + quad) ^ (ra & 7)) << 3)]);
        int rb = wn * 64 + i * 16 + l16;
        bfr[i] = ld8(&lB[rb * 64 + (((ks * 4 + quad) ^ (rb & 7)) << 3)]);
      }
#pragma unroll
      for (int i = 0; i < 4; i++)
#pragma unroll
        for (int j = 0; j < 4; j++)
          acc[i][j] = __builtin_amdgcn_mfma_f32_16x16x32_bf16(af[i], bfr[j], acc[i][j], 0, 0, 0);
    }
  }

#pragma unroll
  for (int i = 0; i < 4; i++) {
    const int row0 = tm + wm * 64 + i * 16 + quad * 4;
#pragma unroll
    for (int j = 0; j < 4; j++) {
      const int col = tn + wn * 64 + j * 16 + l16;
      const float bv = bias[col];
#pragma unroll
      for (int r = 0; r < 4; r++) {
        float v = acc[i][j][r] + bv;
        if (RESID) v += resid[(size_t)(row0 + r) * N + col];
        if (RELU) v = fmaxf(v, 0.f);
        if (OUTBF) Cb[(size_t)(row0 + r) * N + col] = f2bf(v);
        else       Cf[(size_t)(row0 + r) * N + col] = v;
      }
    }
  }
}

// ---------- GEMM 128x64 tile (N=768: 768 blocks) ----------
template <int RESID, int RELU, int OUTBF, int RESBF>
__global__ __launch_bounds__(256, 4)
void gemm_bt64(const u16* __restrict__ A, const u16* __restrict__ BT,
               const float* __restrict__ bias, const float* __restrict__ residf,
               const u16* __restrict__ residb,
               float* __restrict__ Cf, u16* __restrict__ Cb, int N, int K) {
  __shared__ __align__(16) u16 lA[128 * 64];
  __shared__ __align__(16) u16 lB[64 * 64];
  const int tid = threadIdx.x;
  const int wave = tid >> 6, lane = tid & 63;
  const int quad = lane >> 4, l16 = lane & 15;
  const int wm = wave >> 1, wn = wave & 1;
  const int tm = blockIdx.y * 128, tn = blockIdx.x * 64;

  f32x4 acc[4][2] = {};

  for (int k0 = 0; k0 < K; k0 += 64) {
    __syncthreads();
#pragma unroll
    for (int i = 0; i < 4; i++) {
      int cbase = (wave * 4 + i) * 64;
      int c = cbase + lane;
      int row = c >> 3;
      int scc = (c & 7) ^ (row & 7);
      async16(A + (size_t)(tm + row) * K + k0 + scc * 8, &lA[cbase * 8]);
    }
#pragma unroll
    for (int i = 0; i < 2; i++) {
      int cbase = (wave * 2 + i) * 64;
      int c = cbase + lane;
      int row = c >> 3;
      int scc = (c & 7) ^ (row & 7);
      async16(BT + (size_t)(tn + row) * K + k0 + scc * 8, &lB[cbase * 8]);
    }
    __syncthreads();
#pragma unroll
    for (int ks = 0; ks < 2; ks++) {
      bf16x8 af[4], bfr[2];
#pragma unroll
      for (int i = 0; i < 4; i++) {
        int ra = wm * 64 + i * 16 + l16;
        af[i] = ld8(&lA[ra * 64 + (((ks * 4 + quad) ^ (ra & 7)) << 3)]);
      }
#pragma unroll
      for (int j = 0; j < 2; j++) {
        int rb = wn * 32 + j * 16 + l16;
        bfr[j] = ld8(&lB[rb * 64 + (((ks * 4 + quad) ^ (rb & 7)) << 3)]);
      }
#pragma unroll
      for (int i = 0; i < 4; i++)
#pragma unroll
        for (int j = 0; j < 2; j++)
          acc[i][j] = __builtin_amdgcn_mfma_f32_16x16x32_bf16(af[i], bfr[j], acc[i][j], 0, 0, 0);
    }
  }

#pragma unroll
  for (int i = 0; i < 4; i++) {
    const int row0 = tm + wm * 64 + i * 16 + quad * 4;
#pragma unroll
    for (int j = 0; j < 2; j++) {
      const int col = tn + wn * 32 + j * 16 + l16;
      const float bv = bias[col];
#pragma unroll
      for (int r = 0; r < 4; r++) {
        float v = acc[i][j][r] + bv;
        if (RESID) {
          if (RESBF) v += bf2f(residb[(size_t)(row0 + r) * N + col]);
          else       v += residf[(size_t)(row0 + r) * N + col];
        }
        if (RELU) v = fmaxf(v, 0.f);
        if (OUTBF) Cb[(size_t)(row0 + r) * N + col] = f2bf(v);
        else       Cf[(size_t)(row0 + r) * N + col] = v;
      }
    }
  }
}

// ---------- flash attention v12: pipelined QK(t) || PV(t-1), bank-rotating K ----------
// Round-4 post-mortem: dependency-bound (QK->SM->PV serial per iter; MFMA 32%,
// LDS 37%, VALU 43% -- nothing saturated) + KROW=96 added real conflicts.
// Fixes:
//  (a) KROW=104 (13 chunks: 12 data + 1 pad, 208 B row): banks rotate 20/row
//      -> QK reads conflict-free with IDENTITY slot mapping (no XOR). K stage
//      832 chunks (-19% vs padded-16).
//  (b) One-tile software pipeline carrying only packed pa (8 regs):
//      body t = {barrier; stage(t+1); QK(t); PV(t-1); SM(t)->pa}.
//      PV(t-1) is independent of QK(t): both MFMA clusters issue together and
//      SM's VALU overlaps PV's MFMAs. V triple-buffered, K double-buffered.
// LDS = 2*13312 + 3*12288 = 63488 B -> 2 blocks/CU (16 waves/CU).
#define KROW 104  // u16 per K row (13 slots of 8)
#define VROW 64   // u16 per V row (8 slots of 8, XOR-swizzled)

// pack one 16-key slice (8 f32 score regs) into one PV B-fragment.
#define PACK_SLICE(SC, B, DST)                                                   \
  {                                                                              \
    uint32_t u0, u1, u2, u3;                                                     \
    asm("v_cvt_pk_bf16_f32 %0, %1, %2" : "=v"(u0) : "v"(SC[B+0]), "v"(SC[B+1])); \
    asm("v_cvt_pk_bf16_f32 %0, %1, %2" : "=v"(u1) : "v"(SC[B+2]), "v"(SC[B+3])); \
    asm("v_cvt_pk_bf16_f32 %0, %1, %2" : "=v"(u2) : "v"(SC[B+4]), "v"(SC[B+5])); \
    asm("v_cvt_pk_bf16_f32 %0, %1, %2" : "=v"(u3) : "v"(SC[B+6]), "v"(SC[B+7])); \
    asm("v_permlane32_swap_b32 %0, %1" : "+v"(u2), "+v"(u0));                    \
    asm("v_permlane32_swap_b32 %0, %1" : "+v"(u3), "+v"(u1));                    \
    union { uint32_t w[4]; bf16x8 v; } pu_;                                      \
    pu_.w[0] = u0; pu_.w[1] = u1; pu_.w[2] = u2; pu_.w[3] = u3;                  \
    DST = pu_.v;                                                                 \
  }

__global__ __launch_bounds__(512, 4)
void flash_attn(const u16* __restrict__ qkv, const u16* __restrict__ Vt,
                u16* __restrict__ Ob) {
  // flat LDS: K bufs [2][64*104] u16 (26,624 B), V bufs [3][96*64] u16
  // (36,864 B); total 63,488 B. Epilogue aliases as float exchange.
  __shared__ __align__(16) u16 smem[31744];
  const int tid = threadIdx.x, wave = tid >> 6, lane = tid & 63;
  const int l32 = lane & 31, half = lane >> 5;
  const int qsub = wave >> 1, kodd = wave & 1, pair = wave >> 1;
  // XCD-aware decode: lin%8 = XCD; 4 heads/XCD; 16 q-blocks per head.
  const int lin = blockIdx.x;
  const int bh = (lin & 7) * 4 + ((lin >> 3) & 3);
  const int qb = lin >> 5;
  const int b = bh >> 3, h = bh & 7;
  const int q0 = qb * 128 + qsub * 32;
  const u16* Qp = qkv;
  const u16* KpB = qkv + 768 + (size_t)b * SEQ * QKVN + h * DK;
  const u16* VtB = Vt + (size_t)bh * DK * SEQ;
  const float cs = 0.10206207262f * LOG2E;  // (1/sqrt(96)) * log2(e)
  const float Ms = 16.0f * cs;              // fixed shift (folded)

  // Q^T B-fragments: lane holds q = l32, dk = d*16 + half*8 + [0..7]
  bf16x8 qf[6];
#pragma unroll
  for (int d = 0; d < 6; d++)
    qf[d] = ld8(Qp + (size_t)(b * SEQ + q0 + l32) * QKVN + h * DK + d * 16 + half * 8);

  f32x16 of[3] = {};     // O^T partial (this wave's 32-key half): D[dk blk][q=l32]
  float l_lane = 0.f;    // per-lane softmax denom partial
  bf16x8 pa[2];          // packed P fragments carried body->body

  // DMA one K/V tile with 512 threads:
  // K = 832 chunks [64 rows][13 slots] (slot s holds chunk min(s,11));
  // V = 768 chunks [96 rows][8 slots]  (slot s holds chunk (s^row)&7).
  auto stage = [&](int kt, int kb_, int vb_) {
    u16* kd = smem + kb_ * 6656;
    u16* vd = smem + 13312 + vb_ * 6144;
    {
      int sl = tid;                        // 0..511
      int row = sl / 13, s = sl - row * 13;
      int c = s > 11 ? 11 : s;
      async16(KpB + (size_t)(kt + row) * QKVN + c * 8, kd + sl * 8);
    }
    if (tid < 320) {
      int sl = 512 + tid;                  // 512..831
      int row = sl / 13, s = sl - row * 13;
      int c = s > 11 ? 11 : s;
      async16(KpB + (size_t)(kt + row) * QKVN + c * 8, kd + sl * 8);
    }
    {
      int s = tid;
      int row = s >> 3, c = (s ^ row) & 7;
      async16(VtB + (size_t)row * SEQ + kt + c * 8, vd + s * 8);
    }
    if (tid < 256) {
      int s = 512 + tid;
      int row = s >> 3, c = (s ^ row) & 7;
      async16(VtB + (size_t)row * SEQ + kt + c * 8, vd + s * 8);
    }
  };

  stage(0, 0, 0);
  int vs = 1;   // V-buf for next stage (tile t+1)
  int vr = 0;   // V-buf for PV read (tile t-1)
  const int krow = kodd * 32 + l32;

  for (int t = 0; t < 32; t++) {
    __syncthreads();  // drains DMA of tile t; protects bufs being re-staged
    if (t + 1 < 32) stage((t + 1) * 64, (t + 1) & 1, vs);
    vs = (vs == 2) ? 0 : vs + 1;

    // QK(t): S^T = K Q^T for this wave's 32-key half; col = q
    const u16* kd = smem + (t & 1) * 6656;
    f32x16 sc = {};
    __builtin_amdgcn_s_setprio(1);
#pragma unroll
    for (int d = 0; d < 6; d++) {
      bf16x8 kb = ld8(&kd[krow * KROW + (d * 2 + half) * 8]);  // identity slot
      sc = __builtin_amdgcn_mfma_f32_32x32x16_bf16(kb, qf[d], sc, 0, 0, 0);
    }

    // PV(t-1): O^T += V^T P^T (independent of QK(t) -> overlaps)
    if (t > 0) {
      const u16* vd = smem + 13312 + vr * 6144;
      vr = (vr == 2) ? 0 : vr + 1;
#pragma unroll
      for (int ks = 0; ks < 2; ks++) {
        int gv = kodd * 4 + ks * 2 + half;
#pragma unroll
        for (int db = 0; db < 3; db++) {
          int vrow = db * 32 + l32;
          bf16x8 va = ld8(&vd[vrow * VROW + ((gv ^ vrow) & 7) * 8]);
          of[db] = __builtin_amdgcn_mfma_f32_32x32x16_bf16(va, pa[ks], of[db], 0, 0, 0);
        }
      }
    }
    __builtin_amdgcn_s_setprio(0);

    // SM(t): P = exp2(s*cs - Ms); accumulate l; pack into pa for next body
#pragma unroll
    for (int r = 0; r < 16; r++) {
      float p = __builtin_amdgcn_exp2f(sc[r] * cs - Ms);
      l_lane += p;
      sc[r] = p;
    }
    PACK_SLICE(sc, 0, pa[0])
    PACK_SLICE(sc, 8, pa[1])
  }

  // tail: PV(31) (V[31%3=1] staged & drained; no writer follows)
  {
    const u16* vd = smem + 13312 + vr * 6144;
#pragma unroll
    for (int ks = 0; ks < 2; ks++) {
      int gv = kodd * 4 + ks * 2 + half;
#pragma unroll
      for (int db = 0; db < 3; db++) {
        int vrow = db * 32 + l32;
        bf16x8 va = ld8(&vd[vrow * VROW + ((gv ^ vrow) & 7) * 8]);
        of[db] = __builtin_amdgcn_mfma_f32_32x32x16_bf16(va, pa[ks], of[db], 0, 0, 0);
      }
    }
  }

  // ---- epilogue: wave-pair combine via LDS, divide, store ----
  float lw = l_lane + __shfl_xor(l_lane, 32);   // this wave's l per q=l32
  float linv = 0.f;
  float* xf = (float*)smem;
  const int q = q0 + l32;
  u16* Orow = Ob + (size_t)(b * SEQ + q) * DM + h * DK;

  __syncthreads();                               // S1: loop done, smem free
  if (kodd) {                                    // phase A write: of[0,1] + lw
    float* dst = xf + (pair * 64 + lane) * 33;
#pragma unroll
    for (int r = 0; r < 16; r++) { dst[r] = of[0][r]; dst[16 + r] = of[1][r]; }
    dst[32] = lw;
  }
  __syncthreads();                               // S2
  if (!kodd) {
    const float* src = xf + (pair * 64 + lane) * 33;
    linv = 1.f / (lw + src[32]);
#pragma unroll
    for (int db = 0; db < 2; db++)
#pragma unroll
      for (int r = 0; r < 16; r++) {
        int dk = db * 32 + (r & 3) + 8 * (r >> 2) + 4 * half;
        Orow[dk] = f2bf((of[db][r] + src[db * 16 + r]) * linv);
      }
  }
  __syncthreads();                               // S3: phase A reads done
  if (kodd) {                                    // phase B write: of[2]
    float* dst = xf + (pair * 64 + lane) * 16;
#pragma unroll
    for (int r = 0; r < 16; r++) dst[r] = of[2][r];
  }
  __syncthreads();                               // S4
  if (!kodd) {
    const float* src = xf + (pair * 64 + lane) * 16;
#pragma unroll
    for (int r = 0; r < 16; r++) {
      int dk = 64 + (r & 3) + 8 * (r >> 2) + 4 * half;
      Orow[dk] = f2bf((of[2][r] + src[r]) * linv);
    }
  }
}

// ---------- LayerNorm: out = LN(y); outf and/or outb optional ----------
__global__ __launch_bounds__(256)
void ln_kernel(const float* __restrict__ y, const float* __restrict__ g,
               const float* __restrict__ be, float* __restrict__ outf,
               u16* __restrict__ outb) {
  int row = blockIdx.x, t = threadIdx.x;
  const float* yr = y + (size_t)row * DM;
  float v[3], s = 0.f, s2 = 0.f;
#pragma unroll
  for (int i = 0; i < 3; i++) {
    v[i] = yr[t + i * 256];
    s += v[i];
    s2 += v[i] * v[i];
  }
#pragma unroll
  for (int m = 1; m < 64; m <<= 1) {
    s += __shfl_xor(s, m);
    s2 += __shfl_xor(s2, m);
  }
  __shared__ float red[2][4];
  int w = t >> 6;
  if ((t & 63) == 0) { red[0][w] = s; red[1][w] = s2; }
  __syncthreads();
  s = red[0][0] + red[0][1] + red[0][2] + red[0][3];
  s2 = red[1][0] + red[1][1] + red[1][2] + red[1][3];
  float mu = s * (1.f / DM);
  float var = s2 * (1.f / DM) - mu * mu;
  float rs = rsqrtf(var + 1e-5f);
#pragma unroll
  for (int i = 0; i < 3; i++) {
    int e = t + i * 256;
    float o = (v[i] - mu) * rs * g[e] + be[e];
    if (outf) outf[(size_t)row * DM + e] = o;
    if (outb) outb[(size_t)row * DM + e] = f2bf(o);
  }
}

// ---------- workspace layout (bytes) ----------
#define SZ_BF 12582912ull            // 8192*768*2
#define SZ_F  25165824ull            // 8192*768*4
#define O_XB   0ull                                  // x bf16; later attn_out
#define O_WT   (O_XB + SZ_BF)                        // qkv^T concat [2304][768] bf16
#define O_WOT  (O_WT + 3538944ull)
#define O_W1T  (O_WOT + 1179648ull)
#define O_W2T  (O_W1T + 3145728ull)
#define O_QKV  (O_W2T + 3145728ull)                  // [8192][2304] bf16; later x1b + h
#define O_VT   (O_QKV + 37748736ull)                 // [32][96][2048] bf16
#define O_Y    (O_VT + SZ_BF)                        // fp32 pre-LN buffer
#define O_X1F  (O_Y + SZ_F)                          // (unused now)
#define O_BIAS (O_X1F + SZ_F)                        // 2304 fp32 concat qkv bias

extern "C" void kernel_launch(void* const* d_in, const int* in_sizes, int n_in,
                              void* d_out, int out_size, void* d_ws, size_t ws_size,
                              hipStream_t stream) {
  const float* x   = (const float*)d_in[0];
  const float* Wq  = (const float*)d_in[1];
  const float* bq  = (const float*)d_in[2];
  const float* Wk  = (const float*)d_in[3];
  const float* bk  = (const float*)d_in[4];
  const float* Wv  = (const float*)d_in[5];
  const float* bv  = (const float*)d_in[6];
  const float* Wo  = (const float*)d_in[7];
  const float* bo  = (const float*)d_in[8];
  const float* g1  = (const float*)d_in[9];
  const float* be1 = (const float*)d_in[10];
  const float* W1  = (const float*)d_in[11];
  const float* b1  = (const float*)d_in[12];
  const float* W2  = (const float*)d_in[13];
  const float* b2  = (const float*)d_in[14];
  const float* g2  = (const float*)d_in[15];
  const float* be2 = (const float*)d_in[16];
  float* out = (float*)d_out;
  char* ws = (char*)d_ws;

  u16* xb    = (u16*)(ws + O_XB);
  u16* WT    = (u16*)(ws + O_WT);
  u16* WoT   = (u16*)(ws + O_WOT);
  u16* W1T   = (u16*)(ws + O_W1T);
  u16* W2T   = (u16*)(ws + O_W2T);
  u16* qkv   = (u16*)(ws + O_QKV);
  u16* vt    = (u16*)(ws + O_VT);
  float* y   = (float*)(ws + O_Y);
  float* bqkv = (float*)(ws + O_BIAS);
  u16* ao   = xb;                       // alias: xb dead after QKV GEMM
  u16* x1b  = qkv;                      // alias: qkv dead after attention
  u16* hbuf = qkv + (size_t)MTOK * DM;  // h [8192][2048] bf16

  // fused prep (one dispatch)
  prep<<<11529, 256, 0, stream>>>(x, xb, bq, bk, bv, bqkv,
                                  Wq, Wk, Wv, Wo, W1, W2,
                                  WT, WoT, W1T, W2T);

  // QKV projection (fused N=2304)
  gemm_bt<0, 0, 1><<<dim3(18, 64), 256, 0, stream>>>(xb, WT, bqkv, nullptr, nullptr, qkv, QKVN, DM);
  // V^T for PV A-operand
  transpose_v<<<dim3(64, 3, 32), dim3(32, 8), 0, stream>>>(qkv + 1536, vt);
  // attention: 512 blocks x 512 threads (8 waves: 4 q-subs x 2 key-halves)
  flash_attn<<<512, 512, 0, stream>>>(qkv, vt, ao);
  // out projection + residual(x fp32) -> y (fp32): N=768, 128x64 tiles
  gemm_bt64<1, 0, 0, 0><<<dim3(12, 64), 256, 0, stream>>>(ao, WoT, bo, x, nullptr, y, nullptr, DM, DM);
  // LN1 -> x1b (bf16 only; fp32 x1 round-trip eliminated)
  ln_kernel<<<8192, 256, 0, stream>>>(y, g1, be1, nullptr, x1b);
  // FFN1 + ReLU -> h (bf16)
  gemm_bt<0, 1, 1><<<dim3(16, 64), 256, 0, stream>>>(x1b, W1T, b1, nullptr, nullptr, hbuf, DFF, DM);
  // FFN2 + residual(x1b bf16) -> y (fp32): N=768, 128x64 tiles
  gemm_bt64<1, 0, 0, 1><<<dim3(12, 64), 256, 0, stream>>>(hbuf, W2T, b2, nullptr, x1b, y, nullptr, DM, DFF);
  // LN2 -> out
  ln_kernel<<<8192, 256, 0, stream>>>(y, g2, be2, out, nullptr);
}

// Round 6
// 320.308 us; speedup vs baseline: 1.2882x; 1.0637x over previous
//
#include <hip/hip_runtime.h>
#include <cstdint>
#include <cstddef>

typedef unsigned short u16;
typedef __bf16 bf16x8 __attribute__((ext_vector_type(8)));
typedef float f32x4 __attribute__((ext_vector_type(4)));
typedef float f32x16 __attribute__((ext_vector_type(16)));

// ---------- constants ----------
#define BATCH 4
#define SEQ   2048
#define DM    768
#define NH    8
#define DK    96
#define DFF   2048
#define MTOK  8192          // BATCH*SEQ
#define QKVN  2304          // 3*DM
#define LOG2E 1.44269504088896340736f

// ---------- helpers ----------
__device__ __forceinline__ u16 f2bf(float f) {
  union { float f; uint32_t u; } v; v.f = f;
  return (u16)((v.u + 0x7fffu + ((v.u >> 16) & 1u)) >> 16);
}
__device__ __forceinline__ float bf2f(u16 b) {
  union { uint32_t u; float f; } v; v.u = (uint32_t)b << 16;
  return v.f;
}
__device__ __forceinline__ bf16x8 ld8(const u16* p) { return *(const bf16x8*)p; }
__device__ __forceinline__ void async16(const u16* g, u16* l) {
  __builtin_amdgcn_global_load_lds((const __attribute__((address_space(1))) void*)g,
                                   (__attribute__((address_space(3))) void*)l, 16, 0, 0);
}

// ---------- fused prep: cast_bf16 + concat3 + 6 weight transposes ----------
__global__ __launch_bounds__(256)
void prep(const float* __restrict__ x, u16* __restrict__ xb,
          const float* __restrict__ bq, const float* __restrict__ bk,
          const float* __restrict__ bv, float* __restrict__ bqkv,
          const float* __restrict__ Wq, const float* __restrict__ Wk,
          const float* __restrict__ Wv, const float* __restrict__ Wo,
          const float* __restrict__ W1, const float* __restrict__ W2,
          u16* __restrict__ WT, u16* __restrict__ WoT,
          u16* __restrict__ W1T, u16* __restrict__ W2T) {
  __shared__ float t[32][33];
  const int tid = threadIdx.x;
  int bid = blockIdx.x;

  if (bid < 6144) {                       // cast x (8192x768 fp32 -> bf16)
    size_t i = (size_t)bid * 1024 + tid * 4;
    float4 f = *(const float4*)(x + i);
    uint2 o;
    o.x = (unsigned)f2bf(f.x) | ((unsigned)f2bf(f.y) << 16);
    o.y = (unsigned)f2bf(f.z) | ((unsigned)f2bf(f.w) << 16);
    *(uint2*)(xb + i) = o;
    return;
  }
  if (bid < 6153) {                       // concat qkv bias (2304)
    int i = (bid - 6144) * 256 + tid;
    float v = (i < 768) ? bq[i] : (i < 1536) ? bk[i - 768] : bv[i - 1536];
    bqkv[i] = v;
    return;
  }
  bid -= 6153;
  const float* in; u16* out; int C, R, bx, by;
  if (bid < 576)       { in = Wq; out = WT;                 C = 768;  R = 768;  bx = bid % 24;          by = bid / 24; }
  else if (bid < 1152) { in = Wk; out = WT + 768 * 768;     C = 768;  R = 768;  bx = (bid - 576) % 24;  by = (bid - 576) / 24; }
  else if (bid < 1728) { in = Wv; out = WT + 2 * 768 * 768; C = 768;  R = 768;  bx = (bid - 1152) % 24; by = (bid - 1152) / 24; }
  else if (bid < 2304) { in = Wo; out = WoT;                C = 768;  R = 768;  bx = (bid - 1728) % 24; by = (bid - 1728) / 24; }
  else if (bid < 3840) { in = W1; out = W1T;                C = 2048; R = 768;  bx = (bid - 2304) % 64; by = (bid - 2304) / 64; }
  else                 { in = W2; out = W2T;                C = 768;  R = 2048; bx = (bid - 3840) % 24; by = (bid - 3840) / 24; }
  const int r0 = by * 32, c0 = bx * 32;
  const int tx = tid & 31, ty = tid >> 5;
#pragma unroll
  for (int i = 0; i < 4; i++)
    t[ty + i * 8][tx] = in[(size_t)(r0 + ty + i * 8) * C + c0 + tx];
  __syncthreads();
#pragma unroll
  for (int i = 0; i < 4; i++)
    out[(size_t)(c0 + ty + i * 8) * R + r0 + tx] = f2bf(t[tx][ty + i * 8]);
}

// v part of qkv (stride 2304) -> vt [B*H][96][2048] bf16
__global__ void transpose_v(const u16* __restrict__ v, u16* __restrict__ vt) {
  __shared__ u16 t[32][33];
  int bh = blockIdx.z, b = bh >> 3, h = bh & 7;
  int s0 = blockIdx.x * 32, d0 = blockIdx.y * 32;
  int tx = threadIdx.x, ty = threadIdx.y;
#pragma unroll
  for (int i = 0; i < 4; i++)
    t[ty + i * 8][tx] = v[(size_t)(b * SEQ + s0 + ty + i * 8) * QKVN + h * DK + d0 + tx];
  __syncthreads();
#pragma unroll
  for (int i = 0; i < 4; i++)
    vt[(size_t)(bh * DK + d0 + ty + i * 8) * SEQ + s0 + tx] = t[tx][ty + i * 8];
}

// ---------- GEMM: C[M,N] = A[M,K] @ BT[N,K]^T + bias (+resid)(+relu) ----------
// 1-D grid + XCD-chunked bijective swizzle (T1, m204): XCD x owns a contiguous
// row-band of M-tiles (8 tiles x all N-tiles) -> A-band (1.6MB @K=768) + full
// B (3.1-3.5MB) mostly fit the XCD's 4MB L2; tile re-reads become L2 hits.
// Requires gridDim.x % 8 == 0 (1152 / 1024 here).
template <int RESID, int RELU, int OUTBF>
__global__ __launch_bounds__(256, 4)
void gemm_bt(const u16* __restrict__ A, const u16* __restrict__ BT,
             const float* __restrict__ bias, const float* __restrict__ resid,
             float* __restrict__ Cf, u16* __restrict__ Cb, int N, int K) {
  __shared__ __align__(16) u16 lA[128 * 64];
  __shared__ __align__(16) u16 lB[128 * 64];
  const int tid = threadIdx.x;
  const int wave = tid >> 6, lane = tid & 63;
  const int quad = lane >> 4, l16 = lane & 15;
  const int wm = wave >> 1, wn = wave & 1;
  const int q8 = gridDim.x >> 3;
  const int wg = (blockIdx.x & 7) * q8 + (blockIdx.x >> 3);
  const int nbx = N >> 7;
  const int tm = (wg / nbx) * 128, tn = (wg % nbx) * 128;

  f32x4 acc[4][4] = {};

  for (int k0 = 0; k0 < K; k0 += 64) {
    __syncthreads();
#pragma unroll
    for (int i = 0; i < 4; i++) {
      int cbase = (wave * 4 + i) * 64;
      int c = cbase + lane;
      int row = c >> 3;
      int scc = (c & 7) ^ (row & 7);           // XOR swizzle of 16B chunks
      async16(A + (size_t)(tm + row) * K + k0 + scc * 8, &lA[cbase * 8]);
      async16(BT + (size_t)(tn + row) * K + k0 + scc * 8, &lB[cbase * 8]);
    }
    __syncthreads();
#pragma unroll
    for (int ks = 0; ks < 2; ks++) {
      bf16x8 af[4], bfr[4];
#pragma unroll
      for (int i = 0; i < 4; i++) {
        int ra = wm * 64 + i * 16 + l16;
        af[i] = ld8(&lA[ra * 64 + (((ks * 4 + quad) ^ (ra & 7)) << 3)]);
        int rb = wn * 64 + i * 16 + l16;
        bfr[i] = ld8(&lB[rb * 64 + (((ks * 4 + quad) ^ (rb & 7)) << 3)]);
      }
#pragma unroll
      for (int i = 0; i < 4; i++)
#pragma unroll
        for (int j = 0; j < 4; j++)
          acc[i][j] = __builtin_amdgcn_mfma_f32_16x16x32_bf16(af[i], bfr[j], acc[i][j], 0, 0, 0);
    }
  }

#pragma unroll
  for (int i = 0; i < 4; i++) {
    const int row0 = tm + wm * 64 + i * 16 + quad * 4;
#pragma unroll
    for (int j = 0; j < 4; j++) {
      const int col = tn + wn * 64 + j * 16 + l16;
      const float bv = bias[col];
#pragma unroll
      for (int r = 0; r < 4; r++) {
        float v = acc[i][j][r] + bv;
        if (RESID) v += resid[(size_t)(row0 + r) * N + col];
        if (RELU) v = fmaxf(v, 0.f);
        if (OUTBF) Cb[(size_t)(row0 + r) * N + col] = f2bf(v);
        else       Cf[(size_t)(row0 + r) * N + col] = v;
      }
    }
  }
}

// ---------- GEMM 128x64 tile (N=768: 768 blocks), XCD-swizzled ----------
template <int RESID, int RELU, int OUTBF, int RESBF>
__global__ __launch_bounds__(256, 4)
void gemm_bt64(const u16* __restrict__ A, const u16* __restrict__ BT,
               const float* __restrict__ bias, const float* __restrict__ residf,
               const u16* __restrict__ residb,
               float* __restrict__ Cf, u16* __restrict__ Cb, int N, int K) {
  __shared__ __align__(16) u16 lA[128 * 64];
  __shared__ __align__(16) u16 lB[64 * 64];
  const int tid = threadIdx.x;
  const int wave = tid >> 6, lane = tid & 63;
  const int quad = lane >> 4, l16 = lane & 15;
  const int wm = wave >> 1, wn = wave & 1;
  const int q8 = gridDim.x >> 3;
  const int wg = (blockIdx.x & 7) * q8 + (blockIdx.x >> 3);
  const int nbx = N >> 6;
  const int tm = (wg / nbx) * 128, tn = (wg % nbx) * 64;

  f32x4 acc[4][2] = {};

  for (int k0 = 0; k0 < K; k0 += 64) {
    __syncthreads();
#pragma unroll
    for (int i = 0; i < 4; i++) {
      int cbase = (wave * 4 + i) * 64;
      int c = cbase + lane;
      int row = c >> 3;
      int scc = (c & 7) ^ (row & 7);
      async16(A + (size_t)(tm + row) * K + k0 + scc * 8, &lA[cbase * 8]);
    }
#pragma unroll
    for (int i = 0; i < 2; i++) {
      int cbase = (wave * 2 + i) * 64;
      int c = cbase + lane;
      int row = c >> 3;
      int scc = (c & 7) ^ (row & 7);
      async16(BT + (size_t)(tn + row) * K + k0 + scc * 8, &lB[cbase * 8]);
    }
    __syncthreads();
#pragma unroll
    for (int ks = 0; ks < 2; ks++) {
      bf16x8 af[4], bfr[2];
#pragma unroll
      for (int i = 0; i < 4; i++) {
        int ra = wm * 64 + i * 16 + l16;
        af[i] = ld8(&lA[ra * 64 + (((ks * 4 + quad) ^ (ra & 7)) << 3)]);
      }
#pragma unroll
      for (int j = 0; j < 2; j++) {
        int rb = wn * 32 + j * 16 + l16;
        bfr[j] = ld8(&lB[rb * 64 + (((ks * 4 + quad) ^ (rb & 7)) << 3)]);
      }
#pragma unroll
      for (int i = 0; i < 4; i++)
#pragma unroll
        for (int j = 0; j < 2; j++)
          acc[i][j] = __builtin_amdgcn_mfma_f32_16x16x32_bf16(af[i], bfr[j], acc[i][j], 0, 0, 0);
    }
  }

#pragma unroll
  for (int i = 0; i < 4; i++) {
    const int row0 = tm + wm * 64 + i * 16 + quad * 4;
#pragma unroll
    for (int j = 0; j < 2; j++) {
      const int col = tn + wn * 32 + j * 16 + l16;
      const float bv = bias[col];
#pragma unroll
      for (int r = 0; r < 4; r++) {
        float v = acc[i][j][r] + bv;
        if (RESID) {
          if (RESBF) v += bf2f(residb[(size_t)(row0 + r) * N + col]);
          else       v += residf[(size_t)(row0 + r) * N + col];
        }
        if (RELU) v = fmaxf(v, 0.f);
        if (OUTBF) Cb[(size_t)(row0 + r) * N + col] = f2bf(v);
        else       Cf[(size_t)(row0 + r) * N + col] = v;
      }
    }
  }
}

// ---------- flash attention v13: v12 + 4-way l partials ----------
// Round-5 post-mortem: conflicts fixed (8.7M->3.4M) but time ~flat ->
// remaining cost is issue/serial-latency. The l_lane chain was 16 DEPENDENT
// fp adds/tile (not reorderable without fast-math): split into 4 independent
// partials (exposed latency 64 -> ~16 cyc/tile). +3 VGPR, no spill risk.
#define KROW 104  // u16 per K row (13 slots of 8)
#define VROW 64   // u16 per V row (8 slots of 8, XOR-swizzled)

// pack one 16-key slice (8 f32 score regs) into one PV B-fragment.
#define PACK_SLICE(SC, B, DST)                                                   \
  {                                                                              \
    uint32_t u0, u1, u2, u3;                                                     \
    asm("v_cvt_pk_bf16_f32 %0, %1, %2" : "=v"(u0) : "v"(SC[B+0]), "v"(SC[B+1])); \
    asm("v_cvt_pk_bf16_f32 %0, %1, %2" : "=v"(u1) : "v"(SC[B+2]), "v"(SC[B+3])); \
    asm("v_cvt_pk_bf16_f32 %0, %1, %2" : "=v"(u2) : "v"(SC[B+4]), "v"(SC[B+5])); \
    asm("v_cvt_pk_bf16_f32 %0, %1, %2" : "=v"(u3) : "v"(SC[B+6]), "v"(SC[B+7])); \
    asm("v_permlane32_swap_b32 %0, %1" : "+v"(u2), "+v"(u0));                    \
    asm("v_permlane32_swap_b32 %0, %1" : "+v"(u3), "+v"(u1));                    \
    union { uint32_t w[4]; bf16x8 v; } pu_;                                      \
    pu_.w[0] = u0; pu_.w[1] = u1; pu_.w[2] = u2; pu_.w[3] = u3;                  \
    DST = pu_.v;                                                                 \
  }

__global__ __launch_bounds__(512, 4)
void flash_attn(const u16* __restrict__ qkv, const u16* __restrict__ Vt,
                u16* __restrict__ Ob) {
  // flat LDS: K bufs [2][64*104] u16 (26,624 B), V bufs [3][96*64] u16
  // (36,864 B); total 63,488 B. Epilogue aliases as float exchange.
  __shared__ __align__(16) u16 smem[31744];
  const int tid = threadIdx.x, wave = tid >> 6, lane = tid & 63;
  const int l32 = lane & 31, half = lane >> 5;
  const int qsub = wave >> 1, kodd = wave & 1, pair = wave >> 1;
  // XCD-aware decode: lin%8 = XCD; 4 heads/XCD; 16 q-blocks per head.
  const int lin = blockIdx.x;
  const int bh = (lin & 7) * 4 + ((lin >> 3) & 3);
  const int qb = lin >> 5;
  const int b = bh >> 3, h = bh & 7;
  const int q0 = qb * 128 + qsub * 32;
  const u16* Qp = qkv;
  const u16* KpB = qkv + 768 + (size_t)b * SEQ * QKVN + h * DK;
  const u16* VtB = Vt + (size_t)bh * DK * SEQ;
  const float cs = 0.10206207262f * LOG2E;  // (1/sqrt(96)) * log2(e)
  const float Ms = 16.0f * cs;              // fixed shift (folded)

  // Q^T B-fragments: lane holds q = l32, dk = d*16 + half*8 + [0..7]
  bf16x8 qf[6];
#pragma unroll
  for (int d = 0; d < 6; d++)
    qf[d] = ld8(Qp + (size_t)(b * SEQ + q0 + l32) * QKVN + h * DK + d * 16 + half * 8);

  f32x16 of[3] = {};     // O^T partial (this wave's 32-key half): D[dk blk][q=l32]
  float lp[4] = {0.f, 0.f, 0.f, 0.f};  // 4 independent softmax-denom partials
  bf16x8 pa[2];          // packed P fragments carried body->body

  // DMA one K/V tile with 512 threads:
  // K = 832 chunks [64 rows][13 slots] (slot s holds chunk min(s,11));
  // V = 768 chunks [96 rows][8 slots]  (slot s holds chunk (s^row)&7).
  auto stage = [&](int kt, int kb_, int vb_) {
    u16* kd = smem + kb_ * 6656;
    u16* vd = smem + 13312 + vb_ * 6144;
    {
      int sl = tid;                        // 0..511
      int row = sl / 13, s = sl - row * 13;
      int c = s > 11 ? 11 : s;
      async16(KpB + (size_t)(kt + row) * QKVN + c * 8, kd + sl * 8);
    }
    if (tid < 320) {
      int sl = 512 + tid;                  // 512..831
      int row = sl / 13, s = sl - row * 13;
      int c = s > 11 ? 11 : s;
      async16(KpB + (size_t)(kt + row) * QKVN + c * 8, kd + sl * 8);
    }
    {
      int s = tid;
      int row = s >> 3, c = (s ^ row) & 7;
      async16(VtB + (size_t)row * SEQ + kt + c * 8, vd + s * 8);
    }
    if (tid < 256) {
      int s = 512 + tid;
      int row = s >> 3, c = (s ^ row) & 7;
      async16(VtB + (size_t)row * SEQ + kt + c * 8, vd + s * 8);
    }
  };

  stage(0, 0, 0);
  int vs = 1;   // V-buf for next stage (tile t+1)
  int vr = 0;   // V-buf for PV read (tile t-1)
  const int krow = kodd * 32 + l32;

  for (int t = 0; t < 32; t++) {
    __syncthreads();  // drains DMA of tile t; protects bufs being re-staged
    if (t + 1 < 32) stage((t + 1) * 64, (t + 1) & 1, vs);
    vs = (vs == 2) ? 0 : vs + 1;

    // QK(t): S^T = K Q^T for this wave's 32-key half; col = q
    const u16* kd = smem + (t & 1) * 6656;
    f32x16 sc = {};
    __builtin_amdgcn_s_setprio(1);
#pragma unroll
    for (int d = 0; d < 6; d++) {
      bf16x8 kb = ld8(&kd[krow * KROW + (d * 2 + half) * 8]);  // identity slot
      sc = __builtin_amdgcn_mfma_f32_32x32x16_bf16(kb, qf[d], sc, 0, 0, 0);
    }

    // PV(t-1): O^T += V^T P^T (independent of QK(t) -> overlaps)
    if (t > 0) {
      const u16* vd = smem + 13312 + vr * 6144;
      vr = (vr == 2) ? 0 : vr + 1;
#pragma unroll
      for (int ks = 0; ks < 2; ks++) {
        int gv = kodd * 4 + ks * 2 + half;
#pragma unroll
        for (int db = 0; db < 3; db++) {
          int vrow = db * 32 + l32;
          bf16x8 va = ld8(&vd[vrow * VROW + ((gv ^ vrow) & 7) * 8]);
          of[db] = __builtin_amdgcn_mfma_f32_32x32x16_bf16(va, pa[ks], of[db], 0, 0, 0);
        }
      }
    }
    __builtin_amdgcn_s_setprio(0);

    // SM(t): P = exp2(s*cs - Ms); 4 independent l chains; pack into pa
#pragma unroll
    for (int r = 0; r < 16; r++) {
      float p = __builtin_amdgcn_exp2f(sc[r] * cs - Ms);
      lp[r & 3] += p;
      sc[r] = p;
    }
    PACK_SLICE(sc, 0, pa[0])
    PACK_SLICE(sc, 8, pa[1])
  }

  // tail: PV(31) (V[31%3=1] staged & drained; no writer follows)
  {
    const u16* vd = smem + 13312 + vr * 6144;
#pragma unroll
    for (int ks = 0; ks < 2; ks++) {
      int gv = kodd * 4 + ks * 2 + half;
#pragma unroll
      for (int db = 0; db < 3; db++) {
        int vrow = db * 32 + l32;
        bf16x8 va = ld8(&vd[vrow * VROW + ((gv ^ vrow) & 7) * 8]);
        of[db] = __builtin_amdgcn_mfma_f32_32x32x16_bf16(va, pa[ks], of[db], 0, 0, 0);
      }
    }
  }

  // ---- epilogue: wave-pair combine via LDS, divide, store ----
  float l_lane = (lp[0] + lp[1]) + (lp[2] + lp[3]);
  float lw = l_lane + __shfl_xor(l_lane, 32);   // this wave's l per q=l32
  float linv = 0.f;
  float* xf = (float*)smem;
  const int q = q0 + l32;
  u16* Orow = Ob + (size_t)(b * SEQ + q) * DM + h * DK;

  __syncthreads();                               // S1: loop done, smem free
  if (kodd) {                                    // phase A write: of[0,1] + lw
    float* dst = xf + (pair * 64 + lane) * 33;
#pragma unroll
    for (int r = 0; r < 16; r++) { dst[r] = of[0][r]; dst[16 + r] = of[1][r]; }
    dst[32] = lw;
  }
  __syncthreads();                               // S2
  if (!kodd) {
    const float* src = xf + (pair * 64 + lane) * 33;
    linv = 1.f / (lw + src[32]);
#pragma unroll
    for (int db = 0; db < 2; db++)
#pragma unroll
      for (int r = 0; r < 16; r++) {
        int dk = db * 32 + (r & 3) + 8 * (r >> 2) + 4 * half;
        Orow[dk] = f2bf((of[db][r] + src[db * 16 + r]) * linv);
      }
  }
  __syncthreads();                               // S3: phase A reads done
  if (kodd) {                                    // phase B write: of[2]
    float* dst = xf + (pair * 64 + lane) * 16;
#pragma unroll
    for (int r = 0; r < 16; r++) dst[r] = of[2][r];
  }
  __syncthreads();                               // S4
  if (!kodd) {
    const float* src = xf + (pair * 64 + lane) * 16;
#pragma unroll
    for (int r = 0; r < 16; r++) {
      int dk = 64 + (r & 3) + 8 * (r >> 2) + 4 * half;
      Orow[dk] = f2bf((of[2][r] + src[r]) * linv);
    }
  }
}

// ---------- LayerNorm: out = LN(y); outf and/or outb optional ----------
__global__ __launch_bounds__(256)
void ln_kernel(const float* __restrict__ y, const float* __restrict__ g,
               const float* __restrict__ be, float* __restrict__ outf,
               u16* __restrict__ outb) {
  int row = blockIdx.x, t = threadIdx.x;
  const float* yr = y + (size_t)row * DM;
  float v[3], s = 0.f, s2 = 0.f;
#pragma unroll
  for (int i = 0; i < 3; i++) {
    v[i] = yr[t + i * 256];
    s += v[i];
    s2 += v[i] * v[i];
  }
#pragma unroll
  for (int m = 1; m < 64; m <<= 1) {
    s += __shfl_xor(s, m);
    s2 += __shfl_xor(s2, m);
  }
  __shared__ float red[2][4];
  int w = t >> 6;
  if ((t & 63) == 0) { red[0][w] = s; red[1][w] = s2; }
  __syncthreads();
  s = red[0][0] + red[0][1] + red[0][2] + red[0][3];
  s2 = red[1][0] + red[1][1] + red[1][2] + red[1][3];
  float mu = s * (1.f / DM);
  float var = s2 * (1.f / DM) - mu * mu;
  float rs = rsqrtf(var + 1e-5f);
#pragma unroll
  for (int i = 0; i < 3; i++) {
    int e = t + i * 256;
    float o = (v[i] - mu) * rs * g[e] + be[e];
    if (outf) outf[(size_t)row * DM + e] = o;
    if (outb) outb[(size_t)row * DM + e] = f2bf(o);
  }
}

// ---------- workspace layout (bytes) ----------
#define SZ_BF 12582912ull            // 8192*768*2
#define SZ_F  25165824ull            // 8192*768*4
#define O_XB   0ull                                  // x bf16; later attn_out
#define O_WT   (O_XB + SZ_BF)                        // qkv^T concat [2304][768] bf16
#define O_WOT  (O_WT + 3538944ull)
#define O_W1T  (O_WOT + 1179648ull)
#define O_W2T  (O_W1T + 3145728ull)
#define O_QKV  (O_W2T + 3145728ull)                  // [8192][2304] bf16; later x1b + h
#define O_VT   (O_QKV + 37748736ull)                 // [32][96][2048] bf16
#define O_Y    (O_VT + SZ_BF)                        // fp32 pre-LN buffer
#define O_X1F  (O_Y + SZ_F)                          // (unused now)
#define O_BIAS (O_X1F + SZ_F)                        // 2304 fp32 concat qkv bias

extern "C" void kernel_launch(void* const* d_in, const int* in_sizes, int n_in,
                              void* d_out, int out_size, void* d_ws, size_t ws_size,
                              hipStream_t stream) {
  const float* x   = (const float*)d_in[0];
  const float* Wq  = (const float*)d_in[1];
  const float* bq  = (const float*)d_in[2];
  const float* Wk  = (const float*)d_in[3];
  const float* bk  = (const float*)d_in[4];
  const float* Wv  = (const float*)d_in[5];
  const float* bv  = (const float*)d_in[6];
  const float* Wo  = (const float*)d_in[7];
  const float* bo  = (const float*)d_in[8];
  const float* g1  = (const float*)d_in[9];
  const float* be1 = (const float*)d_in[10];
  const float* W1  = (const float*)d_in[11];
  const float* b1  = (const float*)d_in[12];
  const float* W2  = (const float*)d_in[13];
  const float* b2  = (const float*)d_in[14];
  const float* g2  = (const float*)d_in[15];
  const float* be2 = (const float*)d_in[16];
  float* out = (float*)d_out;
  char* ws = (char*)d_ws;

  u16* xb    = (u16*)(ws + O_XB);
  u16* WT    = (u16*)(ws + O_WT);
  u16* WoT   = (u16*)(ws + O_WOT);
  u16* W1T   = (u16*)(ws + O_W1T);
  u16* W2T   = (u16*)(ws + O_W2T);
  u16* qkv   = (u16*)(ws + O_QKV);
  u16* vt    = (u16*)(ws + O_VT);
  float* y   = (float*)(ws + O_Y);
  float* bqkv = (float*)(ws + O_BIAS);
  u16* ao   = xb;                       // alias: xb dead after QKV GEMM
  u16* x1b  = qkv;                      // alias: qkv dead after attention
  u16* hbuf = qkv + (size_t)MTOK * DM;  // h [8192][2048] bf16

  // fused prep (one dispatch)
  prep<<<11529, 256, 0, stream>>>(x, xb, bq, bk, bv, bqkv,
                                  Wq, Wk, Wv, Wo, W1, W2,
                                  WT, WoT, W1T, W2T);

  // QKV projection (fused N=2304): 18x64 tiles, XCD-swizzled 1-D grid
  gemm_bt<0, 0, 1><<<1152, 256, 0, stream>>>(xb, WT, bqkv, nullptr, nullptr, qkv, QKVN, DM);
  // V^T for PV A-operand
  transpose_v<<<dim3(64, 3, 32), dim3(32, 8), 0, stream>>>(qkv + 1536, vt);
  // attention: 512 blocks x 512 threads (8 waves: 4 q-subs x 2 key-halves)
  flash_attn<<<512, 512, 0, stream>>>(qkv, vt, ao);
  // out projection + residual(x fp32) -> y (fp32): 12x64 tiles, swizzled
  gemm_bt64<1, 0, 0, 0><<<768, 256, 0, stream>>>(ao, WoT, bo, x, nullptr, y, nullptr, DM, DM);
  // LN1 -> x1b (bf16 only; fp32 x1 round-trip eliminated)
  ln_kernel<<<8192, 256, 0, stream>>>(y, g1, be1, nullptr, x1b);
  // FFN1 + ReLU -> h (bf16): 16x64 tiles, swizzled
  gemm_bt<0, 1, 1><<<1024, 256, 0, stream>>>(x1b, W1T, b1, nullptr, nullptr, hbuf, DFF, DM);
  // FFN2 + residual(x1b bf16) -> y (fp32): 12x64 tiles, swizzled
  gemm_bt64<1, 0, 0, 1><<<768, 256, 0, stream>>>(hbuf, W2T, b2, nullptr, x1b, y, nullptr, DM, DFF);
  // LN2 -> out
  ln_kernel<<<8192, 256, 0, stream>>>(y, g2, be2, out, nullptr);
}